// Round 1
// baseline (1449.761 us; speedup 1.0000x reference)
//
#include <hip/hip_runtime.h>
#include <hip/hip_bf16.h>

#define N_NODES 50000
#define NUM_E   800000
#define EPS_BN  1e-5f
#define NUM_GRAPHS 64

// ---------------- CSR build ----------------
__global__ void hist_kernel(const int* __restrict__ ei, int* __restrict__ deg) {
    int e = blockIdx.x * blockDim.x + threadIdx.x;
    if (e >= NUM_E) return;
    atomicAdd(&deg[ei[NUM_E + e]], 1);
}

__global__ void scan_kernel(const int* __restrict__ deg, int* __restrict__ rowptr) {
    __shared__ int sdata[1024];
    __shared__ int carry_s;
    int t = threadIdx.x;
    if (t == 0) { carry_s = 0; rowptr[0] = 0; }
    __syncthreads();
    for (int base = 0; base < N_NODES; base += 1024) {
        int v = (base + t < N_NODES) ? deg[base + t] : 0;
        sdata[t] = v;
        __syncthreads();
        for (int off = 1; off < 1024; off <<= 1) {
            int add = (t >= off) ? sdata[t - off] : 0;
            __syncthreads();
            sdata[t] += add;
            __syncthreads();
        }
        int incl = sdata[t];
        int base_carry = carry_s;
        __syncthreads();
        if (base + t < N_NODES) rowptr[base + t + 1] = base_carry + incl;
        if (t == 1023) carry_s = base_carry + incl;
        __syncthreads();
    }
}

__global__ void scatter_kernel(const int* __restrict__ ei, const int* __restrict__ rowptr,
                               int* __restrict__ fill, int* __restrict__ srcs) {
    int e = blockIdx.x * blockDim.x + threadIdx.x;
    if (e >= NUM_E) return;
    int dst = ei[NUM_E + e];
    int pos = rowptr[dst] + atomicAdd(&fill[dst], 1);
    srcs[pos] = ei[e];
}

// ---------------- GEMM: C[N, Ncols] = A[N, K] * B[K, Ncols] ----------------
template<int K>
__global__ __launch_bounds__(256) void gemm_kernel(const float* __restrict__ A,
                                                   const float* __restrict__ B,
                                                   float* __restrict__ C, int Ncols) {
    __shared__ float As[16][68];   // [k][m], pad keeps 16B alignment, 2-way bank alias (free)
    __shared__ float Bs[16][68];   // [k][n]
    int tid = threadIdx.x;
    int tx = tid & 15, ty = tid >> 4;
    int row0 = blockIdx.x * 64;
    int col0 = blockIdx.y * 64;
    float acc[4][4] = {};
    for (int k0 = 0; k0 < K; k0 += 16) {
#pragma unroll
        for (int j = 0; j < 4; ++j) {
            int idx = tid + 256 * j;
            int m = idx >> 4, kk = idx & 15;
            int r = row0 + m;
            As[kk][m] = (r < N_NODES) ? A[(long)r * K + k0 + kk] : 0.f;
        }
#pragma unroll
        for (int j = 0; j < 4; ++j) {
            int idx = tid + 256 * j;
            int kk = idx >> 6, n = idx & 63;
            Bs[kk][n] = B[(long)(k0 + kk) * Ncols + col0 + n];
        }
        __syncthreads();
#pragma unroll
        for (int kk = 0; kk < 16; ++kk) {
            float4 av = *(const float4*)&As[kk][ty * 4];
            float4 bv = *(const float4*)&Bs[kk][tx * 4];
            float a[4] = {av.x, av.y, av.z, av.w};
            float b[4] = {bv.x, bv.y, bv.z, bv.w};
#pragma unroll
            for (int i = 0; i < 4; ++i)
#pragma unroll
                for (int j = 0; j < 4; ++j) acc[i][j] += a[i] * b[j];
        }
        __syncthreads();
    }
#pragma unroll
    for (int i = 0; i < 4; ++i) {
        int r = row0 + ty * 4 + i;
        if (r < N_NODES) {
#pragma unroll
            for (int j = 0; j < 4; ++j)
                C[(long)r * Ncols + col0 + tx * 4 + j] = acc[i][j];
        }
    }
}

// ---------------- per-node attention logits ----------------
template<int H>
__global__ void logits_kernel(const float* __restrict__ h, const float* __restrict__ a_src,
                              const float* __restrict__ a_dst,
                              float* __restrict__ as_, float* __restrict__ ad_) {
    int i = blockIdx.x * blockDim.x + threadIdx.x;
    if (i >= N_NODES * H) return;
    int n = i / H, hh = i % H;
    const float* hp  = h + (long)n * H * 64 + hh * 64;
    const float* asp = a_src + hh * 64;
    const float* adp = a_dst + hh * 64;
    float s1 = 0.f, s2 = 0.f;
#pragma unroll
    for (int c = 0; c < 64; c += 4) {
        float4 hv = *(const float4*)(hp + c);
        float4 av = *(const float4*)(asp + c);
        float4 dv = *(const float4*)(adp + c);
        s1 += hv.x * av.x + hv.y * av.y + hv.z * av.z + hv.w * av.w;
        s2 += hv.x * dv.x + hv.y * dv.y + hv.z * dv.z + hv.w * dv.w;
    }
    as_[i] = s1;
    ad_[i] = s2;
}

// ---------------- GAT aggregation: one wave per dst node ----------------
template<int H>
__global__ __launch_bounds__(256) void agg_kernel(const float* __restrict__ h,
                                                  const float* __restrict__ as_,
                                                  const float* __restrict__ ad_,
                                                  const int* __restrict__ rowptr,
                                                  const int* __restrict__ srcs,
                                                  const float* __restrict__ bias,
                                                  float* __restrict__ out) {
    const int CH = H * 64;
    int lane = threadIdx.x & 63;
    int wave = threadIdx.x >> 6;
    int n = blockIdx.x * 4 + wave;
    if (n >= N_NODES) return;
    int start = rowptr[n], end = rowptr[n + 1];
    int deg = end - start;

    float ad[H];
#pragma unroll
    for (int hh = 0; hh < H; ++hh) ad[hh] = ad_[n * H + hh];

    // pass 1: segment max
    float mx[H];
#pragma unroll
    for (int hh = 0; hh < H; ++hh) mx[hh] = -1e30f;
    for (int j = lane; j < deg; j += 64) {
        int s = srcs[start + j];
#pragma unroll
        for (int hh = 0; hh < H; ++hh) {
            float v = as_[s * H + hh] + ad[hh];
            v = v > 0.f ? v : 0.2f * v;
            mx[hh] = fmaxf(mx[hh], v);
        }
    }
#pragma unroll
    for (int m = 1; m < 64; m <<= 1)
#pragma unroll
        for (int hh = 0; hh < H; ++hh) mx[hh] = fmaxf(mx[hh], __shfl_xor(mx[hh], m, 64));

    // pass 2: exp-sum
    float dn[H];
#pragma unroll
    for (int hh = 0; hh < H; ++hh) dn[hh] = 0.f;
    for (int j = lane; j < deg; j += 64) {
        int s = srcs[start + j];
#pragma unroll
        for (int hh = 0; hh < H; ++hh) {
            float v = as_[s * H + hh] + ad[hh];
            v = v > 0.f ? v : 0.2f * v;
            dn[hh] += __expf(v - mx[hh]);
        }
    }
#pragma unroll
    for (int m = 1; m < 64; m <<= 1)
#pragma unroll
        for (int hh = 0; hh < H; ++hh) dn[hh] += __shfl_xor(dn[hh], m, 64);
    float inv[H];
#pragma unroll
    for (int hh = 0; hh < H; ++hh) inv[hh] = dn[hh] > 0.f ? 1.f / dn[hh] : 0.f;

    // pass 3: weighted gather-reduce, alpha broadcast via shuffles
    float acc[H];
#pragma unroll
    for (int hh = 0; hh < H; ++hh) acc[hh] = 0.f;
    for (int chunk = 0; chunk < deg; chunk += 64) {
        int j = chunk + lane;
        float alpha[H];
        int s = 0;
        if (j < deg) {
            s = srcs[start + j];
#pragma unroll
            for (int hh = 0; hh < H; ++hh) {
                float v = as_[s * H + hh] + ad[hh];
                v = v > 0.f ? v : 0.2f * v;
                alpha[hh] = __expf(v - mx[hh]) * inv[hh];
            }
        } else {
#pragma unroll
            for (int hh = 0; hh < H; ++hh) alpha[hh] = 0.f;
        }
        int cnt = min(64, deg - chunk);
        for (int e = 0; e < cnt; ++e) {
            int se = __shfl(s, e, 64);
            const float* hr = h + (long)se * CH;
#pragma unroll
            for (int hh = 0; hh < H; ++hh) {
                float al = __shfl(alpha[hh], e, 64);
                acc[hh] += al * hr[hh * 64 + lane];
            }
        }
    }
#pragma unroll
    for (int hh = 0; hh < H; ++hh) {
        int c = hh * 64 + lane;
        float v = acc[hh] + bias[c];
        out[(long)n * CH + c] = v > 0.f ? v : 0.f;   // fused +bias and ReLU
    }
}

// ---------------- BatchNorm ----------------
__global__ void bn_stats_kernel(const float* __restrict__ x, float* __restrict__ stats, int C) {
    int c = threadIdx.x;
    if (c >= C) return;
    float s = 0.f, s2 = 0.f;
    for (int n = blockIdx.x; n < N_NODES; n += gridDim.x) {
        float v = x[(long)n * C + c];
        s += v;
        s2 += v * v;
    }
    atomicAdd(&stats[c], s);
    atomicAdd(&stats[256 + c], s2);
}

__global__ void bn_apply_kernel(float* __restrict__ x, const float* __restrict__ stats,
                                const float* __restrict__ g, const float* __restrict__ be,
                                int C, long total) {
    long i = (long)blockIdx.x * blockDim.x + threadIdx.x;
    if (i >= total) return;
    int c = (int)(i % C);
    float mean = stats[c] * (1.f / N_NODES);
    float var  = fmaxf(stats[256 + c] * (1.f / N_NODES) - mean * mean, 0.f);
    x[i] = (x[i] - mean) * rsqrtf(var + EPS_BN) * g[c] + be[c];
}

// ---------------- global mean pool + FC ----------------
__global__ void pool_kernel(const float* __restrict__ h, const int* __restrict__ batch,
                            float* __restrict__ pooled, float* __restrict__ cnt) {
    int i = blockIdx.x * blockDim.x + threadIdx.x;
    if (i >= N_NODES * 64) return;
    int n = i >> 6, c = i & 63;
    int g = batch[n];
    atomicAdd(&pooled[g * 64 + c], h[i]);
    if (c == 0) atomicAdd(&cnt[g], 1.f);
}

__global__ void fc_kernel(const float* __restrict__ pooled, const float* __restrict__ cnt,
                          const float* __restrict__ fcW, const float* __restrict__ fcb,
                          float* __restrict__ out) {
    int i = blockIdx.x * blockDim.x + threadIdx.x;
    if (i >= NUM_GRAPHS * 10) return;
    int g = i / 10, j = i % 10;
    float invc = 1.f / fmaxf(cnt[g], 1.f);
    float s = 0.f;
    for (int k = 0; k < 64; ++k) s += pooled[g * 64 + k] * fcW[k * 10 + j];
    out[i] = s * invc + fcb[j];
}

extern "C" void kernel_launch(void* const* d_in, const int* in_sizes, int n_in,
                              void* d_out, int out_size, void* d_ws, size_t ws_size,
                              hipStream_t stream) {
    const float* x       = (const float*)d_in[0];
    const int*   ei      = (const int*)d_in[1];
    const int*   batch   = (const int*)d_in[2];
    const float* W1      = (const float*)d_in[3];
    const float* a_src1  = (const float*)d_in[4];
    const float* a_dst1  = (const float*)d_in[5];
    const float* b1      = (const float*)d_in[6];
    const float* g1      = (const float*)d_in[7];
    const float* be1     = (const float*)d_in[8];
    const float* W2      = (const float*)d_in[9];
    const float* a_src2  = (const float*)d_in[10];
    const float* a_dst2  = (const float*)d_in[11];
    const float* b2      = (const float*)d_in[12];
    const float* g2      = (const float*)d_in[13];
    const float* be2     = (const float*)d_in[14];
    const float* W3      = (const float*)d_in[15];
    const float* a_src3  = (const float*)d_in[16];
    const float* a_dst3  = (const float*)d_in[17];
    const float* b3      = (const float*)d_in[18];
    const float* g3      = (const float*)d_in[19];
    const float* be3     = (const float*)d_in[20];
    const float* fcW     = (const float*)d_in[21];
    const float* fcb     = (const float*)d_in[22];
    float* out = (float*)d_out;

    const size_t N = N_NODES, E = NUM_E;
    float* bufA  = (float*)d_ws;              // [N,256] GEMM output h
    float* bufB  = bufA + N * 256;            // [N,256] aggregated / normalized
    float* as_   = bufB + N * 256;            // [N,4]
    float* ad_   = as_ + N * 4;               // [N,4]
    int*   deg   = (int*)(ad_ + N * 4);       // [N]
    int*   rowptr= deg + N;                   // [N+1]
    int*   fill  = rowptr + (N + 1);          // [N]
    int*   srcs  = fill + N;                  // [E]
    float* stats = (float*)(srcs + E);        // [512]
    float* pooled= stats + 512;               // [64*64]
    float* cntf  = pooled + 64 * 64;          // [64]

    // CSR build (dst is the same for all three layers)
    hipMemsetAsync(deg, 0, sizeof(int) * (N + (N + 1) + N), stream);
    hist_kernel<<<(NUM_E + 255) / 256, 256, 0, stream>>>(ei, deg);
    scan_kernel<<<1, 1024, 0, stream>>>(deg, rowptr);
    scatter_kernel<<<(NUM_E + 255) / 256, 256, 0, stream>>>(ei, rowptr, fill, srcs);

    // ---- layer 1: in=x[N,128] ----
    gemm_kernel<128><<<dim3(782, 4), 256, 0, stream>>>(x, W1, bufA, 256);
    logits_kernel<4><<<(N_NODES * 4 + 255) / 256, 256, 0, stream>>>(bufA, a_src1, a_dst1, as_, ad_);
    agg_kernel<4><<<(N_NODES + 3) / 4, 256, 0, stream>>>(bufA, as_, ad_, rowptr, srcs, b1, bufB);
    hipMemsetAsync(stats, 0, 512 * sizeof(float), stream);
    bn_stats_kernel<<<256, 256, 0, stream>>>(bufB, stats, 256);
    bn_apply_kernel<<<(N_NODES * 256 + 255) / 256, 256, 0, stream>>>(bufB, stats, g1, be1, 256, (long)N_NODES * 256);

    // ---- layer 2 ----
    gemm_kernel<256><<<dim3(782, 4), 256, 0, stream>>>(bufB, W2, bufA, 256);
    logits_kernel<4><<<(N_NODES * 4 + 255) / 256, 256, 0, stream>>>(bufA, a_src2, a_dst2, as_, ad_);
    agg_kernel<4><<<(N_NODES + 3) / 4, 256, 0, stream>>>(bufA, as_, ad_, rowptr, srcs, b2, bufB);
    hipMemsetAsync(stats, 0, 512 * sizeof(float), stream);
    bn_stats_kernel<<<256, 256, 0, stream>>>(bufB, stats, 256);
    bn_apply_kernel<<<(N_NODES * 256 + 255) / 256, 256, 0, stream>>>(bufB, stats, g2, be2, 256, (long)N_NODES * 256);

    // ---- layer 3: heads=1, out 64 ----
    gemm_kernel<256><<<dim3(782, 1), 256, 0, stream>>>(bufB, W3, bufA, 64);
    logits_kernel<1><<<(N_NODES + 255) / 256, 256, 0, stream>>>(bufA, a_src3, a_dst3, as_, ad_);
    agg_kernel<1><<<(N_NODES + 3) / 4, 256, 0, stream>>>(bufA, as_, ad_, rowptr, srcs, b3, bufB);
    hipMemsetAsync(stats, 0, 512 * sizeof(float), stream);
    bn_stats_kernel<<<256, 64, 0, stream>>>(bufB, stats, 64);
    bn_apply_kernel<<<(N_NODES * 64 + 255) / 256, 256, 0, stream>>>(bufB, stats, g3, be3, 64, (long)N_NODES * 64);

    // ---- pool + FC ----
    hipMemsetAsync(pooled, 0, (64 * 64 + 64) * sizeof(float), stream);
    pool_kernel<<<(N_NODES * 64 + 255) / 256, 256, 0, stream>>>(bufB, batch, pooled, cntf);
    fc_kernel<<<3, 256, 0, stream>>>(pooled, cntf, fcW, fcb, out);
}

// Round 2
// 1297.002 us; speedup vs baseline: 1.1178x; 1.1178x over previous
//
#include <hip/hip_runtime.h>
#include <hip/hip_bf16.h>

#define N_NODES 50000
#define NUM_E   800000
#define EPS_BN  1e-5f
#define NUM_GRAPHS 64

// ---------------- CSR build ----------------
__global__ void hist_kernel(const int* __restrict__ ei, int* __restrict__ deg) {
    int e = blockIdx.x * blockDim.x + threadIdx.x;
    if (e >= NUM_E) return;
    atomicAdd(&deg[ei[NUM_E + e]], 1);
}

__global__ void scan_kernel(const int* __restrict__ deg, int* __restrict__ rowptr) {
    __shared__ int sdata[1024];
    __shared__ int carry_s;
    int t = threadIdx.x;
    if (t == 0) { carry_s = 0; rowptr[0] = 0; }
    __syncthreads();
    for (int base = 0; base < N_NODES; base += 1024) {
        int v = (base + t < N_NODES) ? deg[base + t] : 0;
        sdata[t] = v;
        __syncthreads();
        for (int off = 1; off < 1024; off <<= 1) {
            int add = (t >= off) ? sdata[t - off] : 0;
            __syncthreads();
            sdata[t] += add;
            __syncthreads();
        }
        int incl = sdata[t];
        int base_carry = carry_s;
        __syncthreads();
        if (base + t < N_NODES) rowptr[base + t + 1] = base_carry + incl;
        if (t == 1023) carry_s = base_carry + incl;
        __syncthreads();
    }
}

__global__ void scatter_kernel(const int* __restrict__ ei, const int* __restrict__ rowptr,
                               int* __restrict__ fill, int* __restrict__ srcs) {
    int e = blockIdx.x * blockDim.x + threadIdx.x;
    if (e >= NUM_E) return;
    int dst = ei[NUM_E + e];
    int pos = rowptr[dst] + atomicAdd(&fill[dst], 1);
    srcs[pos] = ei[e];
}

// ---------------- GEMM: C[N, Ncols] = A[N, K] * B[K, Ncols] ----------------
template<int K>
__global__ __launch_bounds__(256) void gemm_kernel(const float* __restrict__ A,
                                                   const float* __restrict__ B,
                                                   float* __restrict__ C, int Ncols) {
    __shared__ float As[16][68];
    __shared__ float Bs[16][68];
    int tid = threadIdx.x;
    int tx = tid & 15, ty = tid >> 4;
    int row0 = blockIdx.x * 64;
    int col0 = blockIdx.y * 64;
    float acc[4][4] = {};
    for (int k0 = 0; k0 < K; k0 += 16) {
#pragma unroll
        for (int j = 0; j < 4; ++j) {
            int idx = tid + 256 * j;
            int m = idx >> 4, kk = idx & 15;
            int r = row0 + m;
            As[kk][m] = (r < N_NODES) ? A[(long)r * K + k0 + kk] : 0.f;
        }
#pragma unroll
        for (int j = 0; j < 4; ++j) {
            int idx = tid + 256 * j;
            int kk = idx >> 6, n = idx & 63;
            Bs[kk][n] = B[(long)(k0 + kk) * Ncols + col0 + n];
        }
        __syncthreads();
#pragma unroll
        for (int kk = 0; kk < 16; ++kk) {
            float4 av = *(const float4*)&As[kk][ty * 4];
            float4 bv = *(const float4*)&Bs[kk][tx * 4];
            float a[4] = {av.x, av.y, av.z, av.w};
            float b[4] = {bv.x, bv.y, bv.z, bv.w};
#pragma unroll
            for (int i = 0; i < 4; ++i)
#pragma unroll
                for (int j = 0; j < 4; ++j) acc[i][j] += a[i] * b[j];
        }
        __syncthreads();
    }
#pragma unroll
    for (int i = 0; i < 4; ++i) {
        int r = row0 + ty * 4 + i;
        if (r < N_NODES) {
#pragma unroll
            for (int j = 0; j < 4; ++j)
                C[(long)r * Ncols + col0 + tx * 4 + j] = acc[i][j];
        }
    }
}

// ---------------- per-node attention logits ----------------
template<int H>
__global__ void logits_kernel(const float* __restrict__ h, const float* __restrict__ a_src,
                              const float* __restrict__ a_dst,
                              float* __restrict__ as_, float* __restrict__ ad_) {
    int i = blockIdx.x * blockDim.x + threadIdx.x;
    if (i >= N_NODES * H) return;
    int n = i / H, hh = i % H;
    const float* hp  = h + (long)n * H * 64 + hh * 64;
    const float* asp = a_src + hh * 64;
    const float* adp = a_dst + hh * 64;
    float s1 = 0.f, s2 = 0.f;
#pragma unroll
    for (int c = 0; c < 64; c += 4) {
        float4 hv = *(const float4*)(hp + c);
        float4 av = *(const float4*)(asp + c);
        float4 dv = *(const float4*)(adp + c);
        s1 += hv.x * av.x + hv.y * av.y + hv.z * av.z + hv.w * av.w;
        s2 += hv.x * dv.x + hv.y * dv.y + hv.z * dv.z + hv.w * dv.w;
    }
    as_[i] = s1;
    ad_[i] = s2;
}

// ---------------- GAT aggregation: one wave per dst node ----------------
template<int H>
__global__ __launch_bounds__(256) void agg_kernel(const float* __restrict__ h,
                                                  const float* __restrict__ as_,
                                                  const float* __restrict__ ad_,
                                                  const int* __restrict__ rowptr,
                                                  const int* __restrict__ srcs,
                                                  const float* __restrict__ bias,
                                                  float* __restrict__ out) {
    const int CH = H * 64;
    int lane = threadIdx.x & 63;
    int wave = threadIdx.x >> 6;
    int n = blockIdx.x * 4 + wave;
    if (n >= N_NODES) return;
    int start = rowptr[n], end = rowptr[n + 1];
    int deg = end - start;

    float ad[H];
#pragma unroll
    for (int hh = 0; hh < H; ++hh) ad[hh] = ad_[n * H + hh];

    float mx[H];
#pragma unroll
    for (int hh = 0; hh < H; ++hh) mx[hh] = -1e30f;
    for (int j = lane; j < deg; j += 64) {
        int s = srcs[start + j];
#pragma unroll
        for (int hh = 0; hh < H; ++hh) {
            float v = as_[s * H + hh] + ad[hh];
            v = v > 0.f ? v : 0.2f * v;
            mx[hh] = fmaxf(mx[hh], v);
        }
    }
#pragma unroll
    for (int m = 1; m < 64; m <<= 1)
#pragma unroll
        for (int hh = 0; hh < H; ++hh) mx[hh] = fmaxf(mx[hh], __shfl_xor(mx[hh], m, 64));

    float dn[H];
#pragma unroll
    for (int hh = 0; hh < H; ++hh) dn[hh] = 0.f;
    for (int j = lane; j < deg; j += 64) {
        int s = srcs[start + j];
#pragma unroll
        for (int hh = 0; hh < H; ++hh) {
            float v = as_[s * H + hh] + ad[hh];
            v = v > 0.f ? v : 0.2f * v;
            dn[hh] += __expf(v - mx[hh]);
        }
    }
#pragma unroll
    for (int m = 1; m < 64; m <<= 1)
#pragma unroll
        for (int hh = 0; hh < H; ++hh) dn[hh] += __shfl_xor(dn[hh], m, 64);
    float inv[H];
#pragma unroll
    for (int hh = 0; hh < H; ++hh) inv[hh] = dn[hh] > 0.f ? 1.f / dn[hh] : 0.f;

    float acc[H];
#pragma unroll
    for (int hh = 0; hh < H; ++hh) acc[hh] = 0.f;
    for (int chunk = 0; chunk < deg; chunk += 64) {
        int j = chunk + lane;
        float alpha[H];
        int s = 0;
        if (j < deg) {
            s = srcs[start + j];
#pragma unroll
            for (int hh = 0; hh < H; ++hh) {
                float v = as_[s * H + hh] + ad[hh];
                v = v > 0.f ? v : 0.2f * v;
                alpha[hh] = __expf(v - mx[hh]) * inv[hh];
            }
        } else {
#pragma unroll
            for (int hh = 0; hh < H; ++hh) alpha[hh] = 0.f;
        }
        int cnt = min(64, deg - chunk);
        for (int e = 0; e < cnt; ++e) {
            int se = __shfl(s, e, 64);
            const float* hr = h + (long)se * CH;
#pragma unroll
            for (int hh = 0; hh < H; ++hh) {
                float al = __shfl(alpha[hh], e, 64);
                acc[hh] += al * hr[hh * 64 + lane];
            }
        }
    }
#pragma unroll
    for (int hh = 0; hh < H; ++hh) {
        int c = hh * 64 + lane;
        float v = acc[hh] + bias[c];
        out[(long)n * CH + c] = v > 0.f ? v : 0.f;
    }
}

// ---------------- BatchNorm ----------------
__global__ void bn_stats_kernel(const float* __restrict__ x, float* __restrict__ stats, int C) {
    int c = threadIdx.x;
    if (c >= C) return;
    float s = 0.f, s2 = 0.f;
    for (int n = blockIdx.x; n < N_NODES; n += gridDim.x) {
        float v = x[(long)n * C + c];
        s += v;
        s2 += v * v;
    }
    atomicAdd(&stats[c], s);
    atomicAdd(&stats[256 + c], s2);
}

__global__ void bn_apply_kernel(float* __restrict__ x, const float* __restrict__ stats,
                                const float* __restrict__ g, const float* __restrict__ be,
                                int C, long total) {
    long i = (long)blockIdx.x * blockDim.x + threadIdx.x;
    if (i >= total) return;
    int c = (int)(i % C);
    float mean = stats[c] * (1.f / N_NODES);
    float var  = fmaxf(stats[256 + c] * (1.f / N_NODES) - mean * mean, 0.f);
    x[i] = (x[i] - mean) * rsqrtf(var + EPS_BN) * g[c] + be[c];
}

// ---------------- pool: batch is SORTED -> per-graph contiguous ranges ----------------
__global__ void batch_hist_kernel(const int* __restrict__ batch, int* __restrict__ gcnt) {
    int i = blockIdx.x * blockDim.x + threadIdx.x;
    if (i >= N_NODES) return;
    atomicAdd(&gcnt[batch[i]], 1);   // sorted -> wave-uniform -> ~1 atomic/wave
}

__global__ void batch_scan_kernel(const int* __restrict__ gcnt, int* __restrict__ goff) {
    int t = threadIdx.x;  // 64 threads, one wave
    int incl = gcnt[t];
#pragma unroll
    for (int off = 1; off < 64; off <<= 1) {
        int u = __shfl_up(incl, off, 64);
        if (t >= off) incl += u;
    }
    goff[t + 1] = incl;
    if (t == 0) goff[0] = 0;
}

// one block per graph: direct coalesced mean over node range, no atomics
__global__ __launch_bounds__(256) void pool2_kernel(const float* __restrict__ h,
                                                    const int* __restrict__ goff,
                                                    float* __restrict__ pooled) {
    int g = blockIdx.x;
    int c = threadIdx.x & 63;
    int ty = threadIdx.x >> 6;
    int s = goff[g], e = goff[g + 1];
    float sum = 0.f;
    for (int n = s + ty; n < e; n += 4) sum += h[(long)n * 64 + c];
    __shared__ float red[4][64];
    red[ty][c] = sum;
    __syncthreads();
    if (ty == 0) {
        float tot = red[0][c] + red[1][c] + red[2][c] + red[3][c];
        pooled[g * 64 + c] = tot / fmaxf((float)(e - s), 1.f);
    }
}

__global__ void fc_kernel(const float* __restrict__ pooled, const float* __restrict__ fcW,
                          const float* __restrict__ fcb, float* __restrict__ out) {
    int i = blockIdx.x * blockDim.x + threadIdx.x;
    if (i >= NUM_GRAPHS * 10) return;
    int g = i / 10, j = i % 10;
    float s = 0.f;
    for (int k = 0; k < 64; ++k) s += pooled[g * 64 + k] * fcW[k * 10 + j];
    out[i] = s + fcb[j];
}

extern "C" void kernel_launch(void* const* d_in, const int* in_sizes, int n_in,
                              void* d_out, int out_size, void* d_ws, size_t ws_size,
                              hipStream_t stream) {
    const float* x       = (const float*)d_in[0];
    const int*   ei      = (const int*)d_in[1];
    const int*   batch   = (const int*)d_in[2];
    const float* W1      = (const float*)d_in[3];
    const float* a_src1  = (const float*)d_in[4];
    const float* a_dst1  = (const float*)d_in[5];
    const float* b1      = (const float*)d_in[6];
    const float* g1      = (const float*)d_in[7];
    const float* be1     = (const float*)d_in[8];
    const float* W2      = (const float*)d_in[9];
    const float* a_src2  = (const float*)d_in[10];
    const float* a_dst2  = (const float*)d_in[11];
    const float* b2      = (const float*)d_in[12];
    const float* g2      = (const float*)d_in[13];
    const float* be2     = (const float*)d_in[14];
    const float* W3      = (const float*)d_in[15];
    const float* a_src3  = (const float*)d_in[16];
    const float* a_dst3  = (const float*)d_in[17];
    const float* b3      = (const float*)d_in[18];
    const float* g3      = (const float*)d_in[19];
    const float* be3     = (const float*)d_in[20];
    const float* fcW     = (const float*)d_in[21];
    const float* fcb     = (const float*)d_in[22];
    float* out = (float*)d_out;

    const size_t N = N_NODES, E = NUM_E;
    float* bufA  = (float*)d_ws;              // [N,256]
    float* bufB  = bufA + N * 256;            // [N,256]
    float* as_   = bufB + N * 256;            // [N,4]
    float* ad_   = as_ + N * 4;               // [N,4]
    int*   deg   = (int*)(ad_ + N * 4);       // [N]
    int*   rowptr= deg + N;                   // [N+1]
    int*   fill  = rowptr + (N + 1);          // [N]
    int*   srcs  = fill + N;                  // [E]
    float* stats = (float*)(srcs + E);        // [512]
    float* pooled= stats + 512;               // [64*64]
    int*   gcnt  = (int*)(pooled + 64 * 64);  // [64]
    int*   goff  = gcnt + 64;                 // [65]

    // CSR build (dst is the same for all three layers)
    hipMemsetAsync(deg, 0, sizeof(int) * (N + (N + 1) + N), stream);
    hipMemsetAsync(gcnt, 0, sizeof(int) * 64, stream);
    hist_kernel<<<(NUM_E + 255) / 256, 256, 0, stream>>>(ei, deg);
    scan_kernel<<<1, 1024, 0, stream>>>(deg, rowptr);
    scatter_kernel<<<(NUM_E + 255) / 256, 256, 0, stream>>>(ei, rowptr, fill, srcs);
    batch_hist_kernel<<<(N_NODES + 255) / 256, 256, 0, stream>>>(batch, gcnt);
    batch_scan_kernel<<<1, 64, 0, stream>>>(gcnt, goff);

    // ---- layer 1 ----
    gemm_kernel<128><<<dim3(782, 4), 256, 0, stream>>>(x, W1, bufA, 256);
    logits_kernel<4><<<(N_NODES * 4 + 255) / 256, 256, 0, stream>>>(bufA, a_src1, a_dst1, as_, ad_);
    agg_kernel<4><<<(N_NODES + 3) / 4, 256, 0, stream>>>(bufA, as_, ad_, rowptr, srcs, b1, bufB);
    hipMemsetAsync(stats, 0, 512 * sizeof(float), stream);
    bn_stats_kernel<<<256, 256, 0, stream>>>(bufB, stats, 256);
    bn_apply_kernel<<<(N_NODES * 256 + 255) / 256, 256, 0, stream>>>(bufB, stats, g1, be1, 256, (long)N_NODES * 256);

    // ---- layer 2 ----
    gemm_kernel<256><<<dim3(782, 4), 256, 0, stream>>>(bufB, W2, bufA, 256);
    logits_kernel<4><<<(N_NODES * 4 + 255) / 256, 256, 0, stream>>>(bufA, a_src2, a_dst2, as_, ad_);
    agg_kernel<4><<<(N_NODES + 3) / 4, 256, 0, stream>>>(bufA, as_, ad_, rowptr, srcs, b2, bufB);
    hipMemsetAsync(stats, 0, 512 * sizeof(float), stream);
    bn_stats_kernel<<<256, 256, 0, stream>>>(bufB, stats, 256);
    bn_apply_kernel<<<(N_NODES * 256 + 255) / 256, 256, 0, stream>>>(bufB, stats, g2, be2, 256, (long)N_NODES * 256);

    // ---- layer 3 ----
    gemm_kernel<256><<<dim3(782, 1), 256, 0, stream>>>(bufB, W3, bufA, 64);
    logits_kernel<1><<<(N_NODES + 255) / 256, 256, 0, stream>>>(bufA, a_src3, a_dst3, as_, ad_);
    agg_kernel<1><<<(N_NODES + 3) / 4, 256, 0, stream>>>(bufA, as_, ad_, rowptr, srcs, b3, bufB);
    hipMemsetAsync(stats, 0, 512 * sizeof(float), stream);
    bn_stats_kernel<<<256, 64, 0, stream>>>(bufB, stats, 64);
    bn_apply_kernel<<<(N_NODES * 64 + 255) / 256, 256, 0, stream>>>(bufB, stats, g3, be3, 64, (long)N_NODES * 64);

    // ---- pool + FC ----
    pool2_kernel<<<NUM_GRAPHS, 256, 0, stream>>>(bufB, goff, pooled);
    fc_kernel<<<3, 256, 0, stream>>>(pooled, fcW, fcb, out);
}

// Round 3
// 1112.500 us; speedup vs baseline: 1.3032x; 1.1658x over previous
//
#include <hip/hip_runtime.h>
#include <hip/hip_bf16.h>

#define N_NODES 50000
#define NUM_E   800000
#define EPS_BN  1e-5f
#define NUM_GRAPHS 64

// ---------------- CSR build ----------------
__global__ void hist_kernel(const int* __restrict__ ei, int* __restrict__ deg) {
    int e = blockIdx.x * blockDim.x + threadIdx.x;
    if (e >= NUM_E) return;
    atomicAdd(&deg[ei[NUM_E + e]], 1);
}

__global__ void scan_kernel(const int* __restrict__ deg, int* __restrict__ rowptr) {
    __shared__ int sdata[1024];
    __shared__ int carry_s;
    int t = threadIdx.x;
    if (t == 0) { carry_s = 0; rowptr[0] = 0; }
    __syncthreads();
    for (int base = 0; base < N_NODES; base += 1024) {
        int v = (base + t < N_NODES) ? deg[base + t] : 0;
        sdata[t] = v;
        __syncthreads();
        for (int off = 1; off < 1024; off <<= 1) {
            int add = (t >= off) ? sdata[t - off] : 0;
            __syncthreads();
            sdata[t] += add;
            __syncthreads();
        }
        int incl = sdata[t];
        int base_carry = carry_s;
        __syncthreads();
        if (base + t < N_NODES) rowptr[base + t + 1] = base_carry + incl;
        if (t == 1023) carry_s = base_carry + incl;
        __syncthreads();
    }
}

__global__ void scatter_kernel(const int* __restrict__ ei, const int* __restrict__ rowptr,
                               int* __restrict__ fill, int* __restrict__ srcs) {
    int e = blockIdx.x * blockDim.x + threadIdx.x;
    if (e >= NUM_E) return;
    int dst = ei[NUM_E + e];
    int pos = rowptr[dst] + atomicAdd(&fill[dst], 1);
    srcs[pos] = ei[e];
}

// ---------------- GEMM: C[N, Ncols] = A[N, K] * B[K, Ncols] ----------------
template<int K>
__global__ __launch_bounds__(256) void gemm_kernel(const float* __restrict__ A,
                                                   const float* __restrict__ B,
                                                   float* __restrict__ C, int Ncols) {
    __shared__ float As[16][68];
    __shared__ float Bs[16][68];
    int tid = threadIdx.x;
    int tx = tid & 15, ty = tid >> 4;
    int row0 = blockIdx.x * 64;
    int col0 = blockIdx.y * 64;
    float acc[4][4] = {};
    for (int k0 = 0; k0 < K; k0 += 16) {
#pragma unroll
        for (int j = 0; j < 4; ++j) {
            int idx = tid + 256 * j;
            int m = idx >> 4, kk = idx & 15;
            int r = row0 + m;
            As[kk][m] = (r < N_NODES) ? A[(long)r * K + k0 + kk] : 0.f;
        }
#pragma unroll
        for (int j = 0; j < 4; ++j) {
            int idx = tid + 256 * j;
            int kk = idx >> 6, n = idx & 63;
            Bs[kk][n] = B[(long)(k0 + kk) * Ncols + col0 + n];
        }
        __syncthreads();
#pragma unroll
        for (int kk = 0; kk < 16; ++kk) {
            float4 av = *(const float4*)&As[kk][ty * 4];
            float4 bv = *(const float4*)&Bs[kk][tx * 4];
            float a[4] = {av.x, av.y, av.z, av.w};
            float b[4] = {bv.x, bv.y, bv.z, bv.w};
#pragma unroll
            for (int i = 0; i < 4; ++i)
#pragma unroll
                for (int j = 0; j < 4; ++j) acc[i][j] += a[i] * b[j];
        }
        __syncthreads();
    }
#pragma unroll
    for (int i = 0; i < 4; ++i) {
        int r = row0 + ty * 4 + i;
        if (r < N_NODES) {
#pragma unroll
            for (int j = 0; j < 4; ++j)
                C[(long)r * Ncols + col0 + tx * 4 + j] = acc[i][j];
        }
    }
}

// ---------------- per-node attention logits ----------------
template<int H>
__global__ void logits_kernel(const float* __restrict__ h, const float* __restrict__ a_src,
                              const float* __restrict__ a_dst,
                              float* __restrict__ as_, float* __restrict__ ad_) {
    int i = blockIdx.x * blockDim.x + threadIdx.x;
    if (i >= N_NODES * H) return;
    int n = i / H, hh = i % H;
    const float* hp  = h + (long)n * H * 64 + hh * 64;
    const float* asp = a_src + hh * 64;
    const float* adp = a_dst + hh * 64;
    float s1 = 0.f, s2 = 0.f;
#pragma unroll
    for (int c = 0; c < 64; c += 4) {
        float4 hv = *(const float4*)(hp + c);
        float4 av = *(const float4*)(asp + c);
        float4 dv = *(const float4*)(adp + c);
        s1 += hv.x * av.x + hv.y * av.y + hv.z * av.z + hv.w * av.w;
        s2 += hv.x * dv.x + hv.y * dv.y + hv.z * dv.z + hv.w * dv.w;
    }
    as_[i] = s1;
    ad_[i] = s2;
}

// ---------------- GAT aggregation: one wave per dst node ----------------
template<int H>
__global__ __launch_bounds__(256) void agg_kernel(const float* __restrict__ h,
                                                  const float* __restrict__ as_,
                                                  const float* __restrict__ ad_,
                                                  const int* __restrict__ rowptr,
                                                  const int* __restrict__ srcs,
                                                  const float* __restrict__ bias,
                                                  float* __restrict__ out) {
    const int CH = H * 64;
    int lane = threadIdx.x & 63;
    int wave = threadIdx.x >> 6;
    int n = blockIdx.x * 4 + wave;
    if (n >= N_NODES) return;
    int start = rowptr[n], end = rowptr[n + 1];
    int deg = end - start;

    float ad[H];
#pragma unroll
    for (int hh = 0; hh < H; ++hh) ad[hh] = ad_[n * H + hh];

    float mx[H];
#pragma unroll
    for (int hh = 0; hh < H; ++hh) mx[hh] = -1e30f;
    for (int j = lane; j < deg; j += 64) {
        int s = srcs[start + j];
#pragma unroll
        for (int hh = 0; hh < H; ++hh) {
            float v = as_[s * H + hh] + ad[hh];
            v = v > 0.f ? v : 0.2f * v;
            mx[hh] = fmaxf(mx[hh], v);
        }
    }
#pragma unroll
    for (int m = 1; m < 64; m <<= 1)
#pragma unroll
        for (int hh = 0; hh < H; ++hh) mx[hh] = fmaxf(mx[hh], __shfl_xor(mx[hh], m, 64));

    float dn[H];
#pragma unroll
    for (int hh = 0; hh < H; ++hh) dn[hh] = 0.f;
    for (int j = lane; j < deg; j += 64) {
        int s = srcs[start + j];
#pragma unroll
        for (int hh = 0; hh < H; ++hh) {
            float v = as_[s * H + hh] + ad[hh];
            v = v > 0.f ? v : 0.2f * v;
            dn[hh] += __expf(v - mx[hh]);
        }
    }
#pragma unroll
    for (int m = 1; m < 64; m <<= 1)
#pragma unroll
        for (int hh = 0; hh < H; ++hh) dn[hh] += __shfl_xor(dn[hh], m, 64);
    float inv[H];
#pragma unroll
    for (int hh = 0; hh < H; ++hh) inv[hh] = dn[hh] > 0.f ? 1.f / dn[hh] : 0.f;

    float acc[H];
#pragma unroll
    for (int hh = 0; hh < H; ++hh) acc[hh] = 0.f;
    for (int chunk = 0; chunk < deg; chunk += 64) {
        int j = chunk + lane;
        float alpha[H];
        int s = 0;
        if (j < deg) {
            s = srcs[start + j];
#pragma unroll
            for (int hh = 0; hh < H; ++hh) {
                float v = as_[s * H + hh] + ad[hh];
                v = v > 0.f ? v : 0.2f * v;
                alpha[hh] = __expf(v - mx[hh]) * inv[hh];
            }
        } else {
#pragma unroll
            for (int hh = 0; hh < H; ++hh) alpha[hh] = 0.f;
        }
        int cnt = min(64, deg - chunk);
        for (int e = 0; e < cnt; ++e) {
            int se = __shfl(s, e, 64);
            const float* hr = h + (long)se * CH;
#pragma unroll
            for (int hh = 0; hh < H; ++hh) {
                float al = __shfl(alpha[hh], e, 64);
                acc[hh] += al * hr[hh * 64 + lane];
            }
        }
    }
#pragma unroll
    for (int hh = 0; hh < H; ++hh) {
        int c = hh * 64 + lane;
        float v = acc[hh] + bias[c];
        out[(long)n * CH + c] = v > 0.f ? v : 0.f;
    }
}

// ---------------- BatchNorm ----------------
__global__ void bn_stats_kernel(const float* __restrict__ x, float* __restrict__ stats, int C) {
    int c = threadIdx.x;
    if (c >= C) return;
    float s = 0.f, s2 = 0.f;
    for (int n = blockIdx.x; n < N_NODES; n += gridDim.x) {
        float v = x[(long)n * C + c];
        s += v;
        s2 += v * v;
    }
    atomicAdd(&stats[c], s);
    atomicAdd(&stats[256 + c], s2);
}

__global__ void bn_apply_kernel(float* __restrict__ x, const float* __restrict__ stats,
                                const float* __restrict__ g, const float* __restrict__ be,
                                int C, long total) {
    long i = (long)blockIdx.x * blockDim.x + threadIdx.x;
    if (i >= total) return;
    int c = (int)(i % C);
    float mean = stats[c] * (1.f / N_NODES);
    float var  = fmaxf(stats[256 + c] * (1.f / N_NODES) - mean * mean, 0.f);
    x[i] = (x[i] - mean) * rsqrtf(var + EPS_BN) * g[c] + be[c];
}

// ---------------- pool: batch is SORTED -> binary-search graph offsets ----------------
__global__ void batch_offsets_kernel(const int* __restrict__ batch, int* __restrict__ goff) {
    int g = threadIdx.x;
    if (g > NUM_GRAPHS) return;
    // lower_bound: first i with batch[i] >= g
    int lo = 0, hi = N_NODES;
    while (lo < hi) {
        int mid = (lo + hi) >> 1;
        if (batch[mid] < g) lo = mid + 1; else hi = mid;
    }
    goff[g] = lo;
}

// one block per graph: direct coalesced mean over node range, no atomics
__global__ __launch_bounds__(256) void pool2_kernel(const float* __restrict__ h,
                                                    const int* __restrict__ goff,
                                                    float* __restrict__ pooled) {
    int g = blockIdx.x;
    int c = threadIdx.x & 63;
    int ty = threadIdx.x >> 6;
    int s = goff[g], e = goff[g + 1];
    float sum = 0.f;
    for (int n = s + ty; n < e; n += 4) sum += h[(long)n * 64 + c];
    __shared__ float red[4][64];
    red[ty][c] = sum;
    __syncthreads();
    if (ty == 0) {
        float tot = red[0][c] + red[1][c] + red[2][c] + red[3][c];
        pooled[g * 64 + c] = tot / fmaxf((float)(e - s), 1.f);
    }
}

__global__ void fc_kernel(const float* __restrict__ pooled, const float* __restrict__ fcW,
                          const float* __restrict__ fcb, float* __restrict__ out) {
    int i = blockIdx.x * blockDim.x + threadIdx.x;
    if (i >= NUM_GRAPHS * 10) return;
    int g = i / 10, j = i % 10;
    float s = 0.f;
    for (int k = 0; k < 64; ++k) s += pooled[g * 64 + k] * fcW[k * 10 + j];
    out[i] = s + fcb[j];
}

extern "C" void kernel_launch(void* const* d_in, const int* in_sizes, int n_in,
                              void* d_out, int out_size, void* d_ws, size_t ws_size,
                              hipStream_t stream) {
    const float* x       = (const float*)d_in[0];
    const int*   ei      = (const int*)d_in[1];
    const int*   batch   = (const int*)d_in[2];
    const float* W1      = (const float*)d_in[3];
    const float* a_src1  = (const float*)d_in[4];
    const float* a_dst1  = (const float*)d_in[5];
    const float* b1      = (const float*)d_in[6];
    const float* g1      = (const float*)d_in[7];
    const float* be1     = (const float*)d_in[8];
    const float* W2      = (const float*)d_in[9];
    const float* a_src2  = (const float*)d_in[10];
    const float* a_dst2  = (const float*)d_in[11];
    const float* b2      = (const float*)d_in[12];
    const float* g2      = (const float*)d_in[13];
    const float* be2     = (const float*)d_in[14];
    const float* W3      = (const float*)d_in[15];
    const float* a_src3  = (const float*)d_in[16];
    const float* a_dst3  = (const float*)d_in[17];
    const float* b3      = (const float*)d_in[18];
    const float* g3      = (const float*)d_in[19];
    const float* be3     = (const float*)d_in[20];
    const float* fcW     = (const float*)d_in[21];
    const float* fcb     = (const float*)d_in[22];
    float* out = (float*)d_out;

    const size_t N = N_NODES, E = NUM_E;
    float* bufA  = (float*)d_ws;              // [N,256]
    float* bufB  = bufA + N * 256;            // [N,256]
    float* as_   = bufB + N * 256;            // [N,4]
    float* ad_   = as_ + N * 4;               // [N,4]
    int*   deg   = (int*)(ad_ + N * 4);       // [N]
    int*   rowptr= deg + N;                   // [N+1]
    int*   fill  = rowptr + (N + 1);          // [N]
    int*   srcs  = fill + N;                  // [E]
    float* stats = (float*)(srcs + E);        // [512]
    float* pooled= stats + 512;               // [64*64]
    int*   goff  = (int*)(pooled + 64 * 64);  // [65]

    // CSR build (dst is the same for all three layers)
    hipMemsetAsync(deg, 0, sizeof(int) * (N + (N + 1) + N), stream);
    hist_kernel<<<(NUM_E + 255) / 256, 256, 0, stream>>>(ei, deg);
    scan_kernel<<<1, 1024, 0, stream>>>(deg, rowptr);
    scatter_kernel<<<(NUM_E + 255) / 256, 256, 0, stream>>>(ei, rowptr, fill, srcs);
    batch_offsets_kernel<<<1, 128, 0, stream>>>(batch, goff);

    // ---- layer 1 ----
    gemm_kernel<128><<<dim3(782, 4), 256, 0, stream>>>(x, W1, bufA, 256);
    logits_kernel<4><<<(N_NODES * 4 + 255) / 256, 256, 0, stream>>>(bufA, a_src1, a_dst1, as_, ad_);
    agg_kernel<4><<<(N_NODES + 3) / 4, 256, 0, stream>>>(bufA, as_, ad_, rowptr, srcs, b1, bufB);
    hipMemsetAsync(stats, 0, 512 * sizeof(float), stream);
    bn_stats_kernel<<<256, 256, 0, stream>>>(bufB, stats, 256);
    bn_apply_kernel<<<(N_NODES * 256 + 255) / 256, 256, 0, stream>>>(bufB, stats, g1, be1, 256, (long)N_NODES * 256);

    // ---- layer 2 ----
    gemm_kernel<256><<<dim3(782, 4), 256, 0, stream>>>(bufB, W2, bufA, 256);
    logits_kernel<4><<<(N_NODES * 4 + 255) / 256, 256, 0, stream>>>(bufA, a_src2, a_dst2, as_, ad_);
    agg_kernel<4><<<(N_NODES + 3) / 4, 256, 0, stream>>>(bufA, as_, ad_, rowptr, srcs, b2, bufB);
    hipMemsetAsync(stats, 0, 512 * sizeof(float), stream);
    bn_stats_kernel<<<256, 256, 0, stream>>>(bufB, stats, 256);
    bn_apply_kernel<<<(N_NODES * 256 + 255) / 256, 256, 0, stream>>>(bufB, stats, g2, be2, 256, (long)N_NODES * 256);

    // ---- layer 3 ----
    gemm_kernel<256><<<dim3(782, 1), 256, 0, stream>>>(bufB, W3, bufA, 64);
    logits_kernel<1><<<(N_NODES + 255) / 256, 256, 0, stream>>>(bufA, a_src3, a_dst3, as_, ad_);
    agg_kernel<1><<<(N_NODES + 3) / 4, 256, 0, stream>>>(bufA, as_, ad_, rowptr, srcs, b3, bufB);
    hipMemsetAsync(stats, 0, 512 * sizeof(float), stream);
    bn_stats_kernel<<<256, 64, 0, stream>>>(bufB, stats, 64);
    bn_apply_kernel<<<(N_NODES * 64 + 255) / 256, 256, 0, stream>>>(bufB, stats, g3, be3, 64, (long)N_NODES * 64);

    // ---- pool + FC ----
    pool2_kernel<<<NUM_GRAPHS, 256, 0, stream>>>(bufB, goff, pooled);
    fc_kernel<<<3, 256, 0, stream>>>(pooled, fcW, fcb, out);
}

// Round 4
// 858.977 us; speedup vs baseline: 1.6878x; 1.2951x over previous
//
#include <hip/hip_runtime.h>
#include <hip/hip_bf16.h>

#define N_NODES 50000
#define NUM_E   800000
#define EPS_BN  1e-5f
#define NUM_GRAPHS 64

typedef __attribute__((ext_vector_type(8))) short bf16x8;
typedef __attribute__((ext_vector_type(4))) float f32x4;
typedef unsigned short ushort_t;
typedef unsigned int uint_t;

static __device__ __forceinline__ unsigned short f2bf(float f) {
    unsigned int u = __float_as_uint(f);
    u += 0x7fffu + ((u >> 16) & 1u);   // RNE
    return (unsigned short)(u >> 16);
}
static __device__ __forceinline__ float bf2f(unsigned short s) {
    return __uint_as_float(((unsigned int)s) << 16);
}

// ---------------- CSR build ----------------
__global__ void hist_kernel(const int* __restrict__ ei, int* __restrict__ deg) {
    int e = blockIdx.x * blockDim.x + threadIdx.x;
    if (e >= NUM_E) return;
    atomicAdd(&deg[ei[NUM_E + e]], 1);
}

__global__ void scan_kernel(const int* __restrict__ deg, int* __restrict__ rowptr) {
    __shared__ int wsum[16];
    __shared__ int total_s;
    int t = threadIdx.x, lane = t & 63, wv = t >> 6;
    int carry = 0;
    if (t == 0) rowptr[0] = 0;
    for (int base = 0; base < N_NODES; base += 1024) {
        int i = base + t;
        int v = (i < N_NODES) ? deg[i] : 0;
        int incl = v;
#pragma unroll
        for (int off = 1; off < 64; off <<= 1) {
            int u = __shfl_up(incl, off, 64);
            if (lane >= off) incl += u;
        }
        if (lane == 63) wsum[wv] = incl;
        __syncthreads();
        if (t < 16) {
            int s = wsum[t];
            int sc = s;
#pragma unroll
            for (int off = 1; off < 16; off <<= 1) {
                int u = __shfl_up(sc, off, 64);
                if (t >= off) sc += u;
            }
            wsum[t] = sc - s;          // exclusive prefix of wave sums
            if (t == 15) total_s = sc;
        }
        __syncthreads();
        if (i < N_NODES) rowptr[i + 1] = carry + wsum[wv] + incl;
        int tot = total_s;
        __syncthreads();
        carry += tot;
    }
}

__global__ void scatter_kernel(const int* __restrict__ ei, const int* __restrict__ rowptr,
                               int* __restrict__ fill, int* __restrict__ srcs) {
    int e = blockIdx.x * blockDim.x + threadIdx.x;
    if (e >= NUM_E) return;
    int dst = ei[NUM_E + e];
    int pos = rowptr[dst] + atomicAdd(&fill[dst], 1);
    srcs[pos] = ei[e];
}

// ---------------- prep: fp32 -> bf16 conversions ----------------
__global__ void cvt_x_kernel(const float* __restrict__ x, ushort_t* __restrict__ xb, long total4) {
    long i = (long)blockIdx.x * blockDim.x + threadIdx.x;
    if (i >= total4) return;
    float4 v = ((const float4*)x)[i];
    uint2 o;
    o.x = (uint_t)f2bf(v.x) | ((uint_t)f2bf(v.y) << 16);
    o.y = (uint_t)f2bf(v.z) | ((uint_t)f2bf(v.w) << 16);
    ((uint2*)xb)[i] = o;
}

// W [K][Ncols] fp32 -> Wt [Ncols][K] bf16
__global__ void prep_w_kernel(const float* __restrict__ W, ushort_t* __restrict__ Wt,
                              int K, int Ncols) {
    int i = blockIdx.x * blockDim.x + threadIdx.x;
    if (i >= K * Ncols) return;
    int k = i / Ncols, n = i % Ncols;
    Wt[n * K + k] = f2bf(W[i]);
}

// ---------------- bf16 MFMA GEMM: C[M,NFULL](bf16) = A[M,K](bf16) @ Bt[NFULL,K]^T ----------------
// BM=128, BN=64, BK=32; 4 waves; wave w owns rows w*32..w*32+31 (2 m-tiles) x 64 cols (4 n-tiles)
template<int K, int NFULL>
__global__ __launch_bounds__(256) void gemm_bf16_kernel(const ushort_t* __restrict__ A,
                                                        const ushort_t* __restrict__ Bt,
                                                        ushort_t* __restrict__ C) {
    __shared__ __align__(16) ushort_t As[128][40];   // 32 used + 8 pad (breaks pow2 banks)
    __shared__ __align__(16) ushort_t Bs[64][40];
    __shared__ __align__(16) ushort_t Cs[4][32][64]; // epilogue transpose, per-wave section
    int tid = threadIdx.x;
    int lane = tid & 63, w = tid >> 6;
    int row0 = blockIdx.x * 128, col0 = blockIdx.y * 64;
    int m_l = lane & 15, q = lane >> 4;

    f32x4 acc[2][4];
#pragma unroll
    for (int r = 0; r < 2; ++r)
#pragma unroll
        for (int c = 0; c < 4; ++c) acc[r][c] = (f32x4){0.f, 0.f, 0.f, 0.f};

    int ar = tid >> 1, ako = (tid & 1) * 16;   // A stage: row, ushort offset
    int br = tid >> 2, bko = (tid & 3) * 8;    // B stage

    for (int k0 = 0; k0 < K; k0 += 32) {
        uint4 a0 = make_uint4(0, 0, 0, 0), a1 = make_uint4(0, 0, 0, 0);
        int gr = row0 + ar;
        if (gr < N_NODES) {
            const ushort_t* ap = A + (long)gr * K + k0 + ako;
            a0 = *(const uint4*)ap;
            a1 = *(const uint4*)(ap + 8);
        }
        uint4 bv = *(const uint4*)(Bt + (long)(col0 + br) * K + k0 + bko);
        *(uint4*)&As[ar][ako] = a0;
        *(uint4*)&As[ar][ako + 8] = a1;
        *(uint4*)&Bs[br][bko] = bv;
        __syncthreads();

        bf16x8 af[2], bf[4];
#pragma unroll
        for (int r = 0; r < 2; ++r)
            af[r] = *(const bf16x8*)&As[w * 32 + r * 16 + m_l][q * 8];
#pragma unroll
        for (int c = 0; c < 4; ++c)
            bf[c] = *(const bf16x8*)&Bs[c * 16 + m_l][q * 8];
#pragma unroll
        for (int r = 0; r < 2; ++r)
#pragma unroll
            for (int c = 0; c < 4; ++c)
                acc[r][c] = __builtin_amdgcn_mfma_f32_16x16x32_bf16(af[r], bf[c], acc[r][c], 0, 0, 0);
        __syncthreads();
    }

    // epilogue: regs (C-layout: col=m_l, row=q*4+i) -> LDS -> coalesced bf16 row stores
#pragma unroll
    for (int r = 0; r < 2; ++r)
#pragma unroll
        for (int c = 0; c < 4; ++c)
#pragma unroll
            for (int i = 0; i < 4; ++i)
                Cs[w][r * 16 + q * 4 + i][c * 16 + m_l] = f2bf(acc[r][c][i]);
    // same-wave LDS RAW: in-order DS pipe, no barrier needed
#pragma unroll
    for (int j = 0; j < 4; ++j) {
        int flat = j * 64 + lane;
        int lr = flat >> 3, ch = flat & 7;
        int gr = row0 + w * 32 + lr;
        if (gr < N_NODES)
            *(uint4*)(C + (long)gr * NFULL + col0 + ch * 8) = *(uint4*)&Cs[w][lr][ch * 8];
    }
}

// ---------------- per-node attention logits (bf16 h) ----------------
template<int H>
__global__ void logits_kernel(const ushort_t* __restrict__ h, const float* __restrict__ a_src,
                              const float* __restrict__ a_dst,
                              float* __restrict__ as_, float* __restrict__ ad_) {
    int i = blockIdx.x * blockDim.x + threadIdx.x;
    if (i >= N_NODES * H) return;
    int n = i / H, hh = i % H;
    const ushort_t* hp = h + (long)n * (H * 64) + hh * 64;
    const float* asp = a_src + hh * 64;
    const float* adp = a_dst + hh * 64;
    float s1 = 0.f, s2 = 0.f;
#pragma unroll
    for (int c = 0; c < 64; c += 8) {
        uint4 u = *(const uint4*)(hp + c);
        float f[8];
        f[0] = __uint_as_float(u.x << 16); f[1] = __uint_as_float(u.x & 0xffff0000u);
        f[2] = __uint_as_float(u.y << 16); f[3] = __uint_as_float(u.y & 0xffff0000u);
        f[4] = __uint_as_float(u.z << 16); f[5] = __uint_as_float(u.z & 0xffff0000u);
        f[6] = __uint_as_float(u.w << 16); f[7] = __uint_as_float(u.w & 0xffff0000u);
#pragma unroll
        for (int k = 0; k < 8; ++k) {
            s1 += f[k] * asp[c + k];
            s2 += f[k] * adp[c + k];
        }
    }
    as_[i] = s1;
    ad_[i] = s2;
}

// ---------------- GAT aggregation H=4 (bf16 h), one wave per dst ----------------
__global__ __launch_bounds__(256) void agg4_kernel(const ushort_t* __restrict__ h,
                                                   const float* __restrict__ as_,
                                                   const float* __restrict__ ad_,
                                                   const int* __restrict__ rowptr,
                                                   const int* __restrict__ srcs,
                                                   const float* __restrict__ bias,
                                                   float* __restrict__ out) {
    __shared__ float alds[4][256];
    int lane = threadIdx.x & 63, w = threadIdx.x >> 6;
    int n = blockIdx.x * 4 + w;
    if (n >= N_NODES) return;
    int start = rowptr[n];
    int deg = rowptr[n + 1] - start;

    float4 adv = *(const float4*)(ad_ + n * 4);
    float ad4[4] = {adv.x, adv.y, adv.z, adv.w};

    // single online-softmax pass (max + sum fused)
    float mx[4] = {-1e30f, -1e30f, -1e30f, -1e30f};
    float dn[4] = {0.f, 0.f, 0.f, 0.f};
    for (int j = lane; j < deg; j += 64) {
        int s = srcs[start + j];
        float4 av = *(const float4*)(as_ + s * 4);
        float vv[4] = {av.x + ad4[0], av.y + ad4[1], av.z + ad4[2], av.w + ad4[3]};
#pragma unroll
        for (int hh = 0; hh < 4; ++hh) {
            float v = vv[hh] > 0.f ? vv[hh] : 0.2f * vv[hh];
            float mn = fmaxf(mx[hh], v);
            dn[hh] = dn[hh] * __expf(mx[hh] - mn) + __expf(v - mn);
            mx[hh] = mn;
        }
    }
#pragma unroll
    for (int off = 1; off < 64; off <<= 1) {
#pragma unroll
        for (int hh = 0; hh < 4; ++hh) {
            float m2 = __shfl_xor(mx[hh], off, 64);
            float d2 = __shfl_xor(dn[hh], off, 64);
            float mn = fmaxf(mx[hh], m2);
            dn[hh] = dn[hh] * __expf(mx[hh] - mn) + d2 * __expf(m2 - mn);
            mx[hh] = mn;
        }
    }
    float inv[4];
#pragma unroll
    for (int hh = 0; hh < 4; ++hh) inv[hh] = dn[hh] > 0.f ? 1.f / dn[hh] : 0.f;

    // weighted gather: lane covers cols 4*lane..4*lane+3 (contiguous 512B/row per wave)
    int hd = lane >> 4;
    float acc0 = 0.f, acc1 = 0.f, acc2 = 0.f, acc3 = 0.f;
    for (int chunk = 0; chunk < deg; chunk += 64) {
        int j = chunk + lane;
        int s = 0;
        float al4[4] = {0.f, 0.f, 0.f, 0.f};
        if (j < deg) {
            s = srcs[start + j];
            float4 av = *(const float4*)(as_ + s * 4);
            float vv[4] = {av.x + ad4[0], av.y + ad4[1], av.z + ad4[2], av.w + ad4[3]};
#pragma unroll
            for (int hh = 0; hh < 4; ++hh) {
                float v = vv[hh] > 0.f ? vv[hh] : 0.2f * vv[hh];
                al4[hh] = __expf(v - mx[hh]) * inv[hh];
            }
        }
        *(float4*)&alds[w][lane * 4] = make_float4(al4[0], al4[1], al4[2], al4[3]);
        int cnt = min(64, deg - chunk);
        for (int e = 0; e < cnt; ++e) {
            int se = __shfl(s, e, 64);
            float al = alds[w][e * 4 + hd];          // broadcast read
            const ushort_t* hr = h + (long)se * 256 + lane * 4;
            uint2 u = *(const uint2*)hr;
            acc0 += al * __uint_as_float(u.x << 16);
            acc1 += al * __uint_as_float(u.x & 0xffff0000u);
            acc2 += al * __uint_as_float(u.y << 16);
            acc3 += al * __uint_as_float(u.y & 0xffff0000u);
        }
    }
    int c0 = lane * 4;
    float4 bv = *(const float4*)(bias + c0);
    float4 o;
    o.x = fmaxf(acc0 + bv.x, 0.f);
    o.y = fmaxf(acc1 + bv.y, 0.f);
    o.z = fmaxf(acc2 + bv.z, 0.f);
    o.w = fmaxf(acc3 + bv.w, 0.f);
    *(float4*)(out + (long)n * 256 + c0) = o;
}

// ---------------- GAT aggregation H=1 ----------------
__global__ __launch_bounds__(256) void agg1_kernel(const ushort_t* __restrict__ h,
                                                   const float* __restrict__ as_,
                                                   const float* __restrict__ ad_,
                                                   const int* __restrict__ rowptr,
                                                   const int* __restrict__ srcs,
                                                   const float* __restrict__ bias,
                                                   float* __restrict__ out) {
    int lane = threadIdx.x & 63, w = threadIdx.x >> 6;
    int n = blockIdx.x * 4 + w;
    if (n >= N_NODES) return;
    int start = rowptr[n];
    int deg = rowptr[n + 1] - start;
    float adn = ad_[n];

    float mx = -1e30f, dn = 0.f;
    for (int j = lane; j < deg; j += 64) {
        int s = srcs[start + j];
        float v = as_[s] + adn;
        v = v > 0.f ? v : 0.2f * v;
        float mn = fmaxf(mx, v);
        dn = dn * __expf(mx - mn) + __expf(v - mn);
        mx = mn;
    }
#pragma unroll
    for (int off = 1; off < 64; off <<= 1) {
        float m2 = __shfl_xor(mx, off, 64);
        float d2 = __shfl_xor(dn, off, 64);
        float mn = fmaxf(mx, m2);
        dn = dn * __expf(mx - mn) + d2 * __expf(m2 - mn);
        mx = mn;
    }
    float inv = dn > 0.f ? 1.f / dn : 0.f;

    float acc = 0.f;
    for (int chunk = 0; chunk < deg; chunk += 64) {
        int j = chunk + lane;
        int s = 0;
        float alpha = 0.f;
        if (j < deg) {
            s = srcs[start + j];
            float v = as_[s] + adn;
            v = v > 0.f ? v : 0.2f * v;
            alpha = __expf(v - mx) * inv;
        }
        int cnt = min(64, deg - chunk);
        for (int e = 0; e < cnt; ++e) {
            int se = __shfl(s, e, 64);
            float al = __shfl(alpha, e, 64);
            acc += al * bf2f(h[(long)se * 64 + lane]);
        }
    }
    float v = acc + bias[lane];
    out[(long)n * 64 + lane] = v > 0.f ? v : 0.f;
}

// ---------------- BatchNorm ----------------
__global__ void bn_stats_kernel(const float* __restrict__ x, float* __restrict__ stats, int C) {
    int c = threadIdx.x;
    if (c >= C) return;
    float s = 0.f, s2 = 0.f;
    for (int n = blockIdx.x; n < N_NODES; n += gridDim.x) {
        float v = x[(long)n * C + c];
        s += v;
        s2 += v * v;
    }
    atomicAdd(&stats[c], s);
    atomicAdd(&stats[256 + c], s2);
}

// read fp32, write normalized bf16 (next GEMM's A operand)
__global__ void bn_apply_bf16_kernel(const float* __restrict__ x, ushort_t* __restrict__ xb,
                                     const float* __restrict__ stats,
                                     const float* __restrict__ g, const float* __restrict__ be,
                                     int C, long total) {
    long i = (long)blockIdx.x * blockDim.x + threadIdx.x;
    if (i >= total) return;
    int c = (int)(i % C);
    float mean = stats[c] * (1.f / N_NODES);
    float var = fmaxf(stats[256 + c] * (1.f / N_NODES) - mean * mean, 0.f);
    xb[i] = f2bf((x[i] - mean) * rsqrtf(var + EPS_BN) * g[c] + be[c]);
}

__global__ void bn_apply_f32_kernel(float* __restrict__ x, const float* __restrict__ stats,
                                    const float* __restrict__ g, const float* __restrict__ be,
                                    int C, long total) {
    long i = (long)blockIdx.x * blockDim.x + threadIdx.x;
    if (i >= total) return;
    int c = (int)(i % C);
    float mean = stats[c] * (1.f / N_NODES);
    float var = fmaxf(stats[256 + c] * (1.f / N_NODES) - mean * mean, 0.f);
    x[i] = (x[i] - mean) * rsqrtf(var + EPS_BN) * g[c] + be[c];
}

// ---------------- pool (batch sorted -> binary search) + FC ----------------
__global__ void batch_offsets_kernel(const int* __restrict__ batch, int* __restrict__ goff) {
    int g = threadIdx.x;
    if (g > NUM_GRAPHS) return;
    int lo = 0, hi = N_NODES;
    while (lo < hi) {
        int mid = (lo + hi) >> 1;
        if (batch[mid] < g) lo = mid + 1; else hi = mid;
    }
    goff[g] = lo;
}

__global__ __launch_bounds__(256) void pool2_kernel(const float* __restrict__ h,
                                                    const int* __restrict__ goff,
                                                    float* __restrict__ pooled) {
    int g = blockIdx.x;
    int c = threadIdx.x & 63;
    int ty = threadIdx.x >> 6;
    int s = goff[g], e = goff[g + 1];
    float sum = 0.f;
    for (int n = s + ty; n < e; n += 4) sum += h[(long)n * 64 + c];
    __shared__ float red[4][64];
    red[ty][c] = sum;
    __syncthreads();
    if (ty == 0) {
        float tot = red[0][c] + red[1][c] + red[2][c] + red[3][c];
        pooled[g * 64 + c] = tot / fmaxf((float)(e - s), 1.f);
    }
}

__global__ void fc_kernel(const float* __restrict__ pooled, const float* __restrict__ fcW,
                          const float* __restrict__ fcb, float* __restrict__ out) {
    int i = blockIdx.x * blockDim.x + threadIdx.x;
    if (i >= NUM_GRAPHS * 10) return;
    int g = i / 10, j = i % 10;
    float s = 0.f;
    for (int k = 0; k < 64; ++k) s += pooled[g * 64 + k] * fcW[k * 10 + j];
    out[i] = s + fcb[j];
}

extern "C" void kernel_launch(void* const* d_in, const int* in_sizes, int n_in,
                              void* d_out, int out_size, void* d_ws, size_t ws_size,
                              hipStream_t stream) {
    const float* x      = (const float*)d_in[0];
    const int*   ei     = (const int*)d_in[1];
    const int*   batch  = (const int*)d_in[2];
    const float* W1     = (const float*)d_in[3];
    const float* a_src1 = (const float*)d_in[4];
    const float* a_dst1 = (const float*)d_in[5];
    const float* b1     = (const float*)d_in[6];
    const float* g1     = (const float*)d_in[7];
    const float* be1    = (const float*)d_in[8];
    const float* W2     = (const float*)d_in[9];
    const float* a_src2 = (const float*)d_in[10];
    const float* a_dst2 = (const float*)d_in[11];
    const float* b2     = (const float*)d_in[12];
    const float* g2     = (const float*)d_in[13];
    const float* be2    = (const float*)d_in[14];
    const float* W3     = (const float*)d_in[15];
    const float* a_src3 = (const float*)d_in[16];
    const float* a_dst3 = (const float*)d_in[17];
    const float* b3     = (const float*)d_in[18];
    const float* g3     = (const float*)d_in[19];
    const float* be3    = (const float*)d_in[20];
    const float* fcW    = (const float*)d_in[21];
    const float* fcb    = (const float*)d_in[22];
    float* out = (float*)d_out;

    const size_t N = N_NODES, E = NUM_E;
    float*    bufB  = (float*)d_ws;                    // [N,256] fp32 agg output
    ushort_t* hbf   = (ushort_t*)(bufB + N * 256);     // [N,256] bf16 GEMM output
    ushort_t* ginp  = hbf + N * 256;                   // [N,256] bf16 GEMM input
    ushort_t* w1t   = ginp + N * 256;                  // [256][128]
    ushort_t* w2t   = w1t + 256 * 128;                 // [256][256]
    ushort_t* w3t   = w2t + 256 * 256;                 // [64][256]
    float*    as_   = (float*)(w3t + 64 * 256);        // [N,4]
    float*    ad_   = as_ + N * 4;                     // [N,4]
    int*      deg   = (int*)(ad_ + N * 4);             // [N]
    int*      rowptr= deg + N;                         // [N+1]
    int*      fill  = rowptr + (N + 1);                // [N]
    int*      srcs  = fill + N;                        // [E]
    float*    stats = (float*)(srcs + E);              // [512]
    float*    pooled= stats + 512;                     // [64*64]
    int*      goff  = (int*)(pooled + 64 * 64);        // [65]

    // ---- CSR + pool offsets + dtype prep ----
    hipMemsetAsync(deg, 0, sizeof(int) * (N + (N + 1) + N), stream);
    hist_kernel<<<(NUM_E + 255) / 256, 256, 0, stream>>>(ei, deg);
    scan_kernel<<<1, 1024, 0, stream>>>(deg, rowptr);
    scatter_kernel<<<(NUM_E + 255) / 256, 256, 0, stream>>>(ei, rowptr, fill, srcs);
    batch_offsets_kernel<<<1, 128, 0, stream>>>(batch, goff);
    cvt_x_kernel<<<(N_NODES * 128 / 4 + 255) / 256, 256, 0, stream>>>(x, ginp, (long)N_NODES * 128 / 4);
    prep_w_kernel<<<(128 * 256 + 255) / 256, 256, 0, stream>>>(W1, w1t, 128, 256);
    prep_w_kernel<<<(256 * 256 + 255) / 256, 256, 0, stream>>>(W2, w2t, 256, 256);
    prep_w_kernel<<<(256 * 64 + 255) / 256, 256, 0, stream>>>(W3, w3t, 256, 64);

    const int GB = (N_NODES + 127) / 128;  // 391

    // ---- layer 1 ----
    gemm_bf16_kernel<128, 256><<<dim3(GB, 4), 256, 0, stream>>>(ginp, w1t, hbf);
    logits_kernel<4><<<(N_NODES * 4 + 255) / 256, 256, 0, stream>>>(hbf, a_src1, a_dst1, as_, ad_);
    agg4_kernel<<<(N_NODES + 3) / 4, 256, 0, stream>>>(hbf, as_, ad_, rowptr, srcs, b1, bufB);
    hipMemsetAsync(stats, 0, 512 * sizeof(float), stream);
    bn_stats_kernel<<<256, 256, 0, stream>>>(bufB, stats, 256);
    bn_apply_bf16_kernel<<<(N_NODES * 256 + 255) / 256, 256, 0, stream>>>(bufB, ginp, stats, g1, be1, 256, (long)N_NODES * 256);

    // ---- layer 2 ----
    gemm_bf16_kernel<256, 256><<<dim3(GB, 4), 256, 0, stream>>>(ginp, w2t, hbf);
    logits_kernel<4><<<(N_NODES * 4 + 255) / 256, 256, 0, stream>>>(hbf, a_src2, a_dst2, as_, ad_);
    agg4_kernel<<<(N_NODES + 3) / 4, 256, 0, stream>>>(hbf, as_, ad_, rowptr, srcs, b2, bufB);
    hipMemsetAsync(stats, 0, 512 * sizeof(float), stream);
    bn_stats_kernel<<<256, 256, 0, stream>>>(bufB, stats, 256);
    bn_apply_bf16_kernel<<<(N_NODES * 256 + 255) / 256, 256, 0, stream>>>(bufB, ginp, stats, g2, be2, 256, (long)N_NODES * 256);

    // ---- layer 3 (H=1, 64 cols) ----
    gemm_bf16_kernel<256, 64><<<dim3(GB, 1), 256, 0, stream>>>(ginp, w3t, hbf);
    logits_kernel<1><<<(N_NODES + 255) / 256, 256, 0, stream>>>(hbf, a_src3, a_dst3, as_, ad_);
    agg1_kernel<<<(N_NODES + 3) / 4, 256, 0, stream>>>(hbf, as_, ad_, rowptr, srcs, b3, bufB);
    hipMemsetAsync(stats, 0, 512 * sizeof(float), stream);
    bn_stats_kernel<<<256, 64, 0, stream>>>(bufB, stats, 64);
    bn_apply_f32_kernel<<<(N_NODES * 64 + 255) / 256, 256, 0, stream>>>(bufB, stats, g3, be3, 64, (long)N_NODES * 64);

    // ---- pool + FC ----
    pool2_kernel<<<NUM_GRAPHS, 256, 0, stream>>>(bufB, goff, pooled);
    fc_kernel<<<3, 256, 0, stream>>>(pooled, fcW, fcb, out);
}

// Round 5
// 799.163 us; speedup vs baseline: 1.8141x; 1.0748x over previous
//
#include <hip/hip_runtime.h>
#include <hip/hip_bf16.h>

#define N_NODES 50000
#define NUM_E   800000
#define EPS_BN  1e-5f
#define NUM_GRAPHS 64

typedef __attribute__((ext_vector_type(8))) short bf16x8;
typedef __attribute__((ext_vector_type(4))) float f32x4;
typedef unsigned short ushort_t;
typedef unsigned int uint_t;

static __device__ __forceinline__ unsigned short f2bf(float f) {
    unsigned int u = __float_as_uint(f);
    u += 0x7fffu + ((u >> 16) & 1u);   // RNE
    return (unsigned short)(u >> 16);
}
static __device__ __forceinline__ float bflo(uint_t u) { return __uint_as_float(u << 16); }
static __device__ __forceinline__ float bfhi(uint_t u) { return __uint_as_float(u & 0xffff0000u); }

// ---------------- CSR build ----------------
__global__ void hist_kernel(const int* __restrict__ ei, int* __restrict__ deg) {
    int e = blockIdx.x * blockDim.x + threadIdx.x;
    if (e >= NUM_E) return;
    atomicAdd(&deg[ei[NUM_E + e]], 1);
}

__global__ void scan_kernel(const int* __restrict__ deg, int* __restrict__ rowptr) {
    __shared__ int wsum[16];
    __shared__ int total_s;
    int t = threadIdx.x, lane = t & 63, wv = t >> 6;
    int carry = 0;
    if (t == 0) rowptr[0] = 0;
    for (int base = 0; base < N_NODES; base += 1024) {
        int i = base + t;
        int v = (i < N_NODES) ? deg[i] : 0;
        int incl = v;
#pragma unroll
        for (int off = 1; off < 64; off <<= 1) {
            int u = __shfl_up(incl, off, 64);
            if (lane >= off) incl += u;
        }
        if (lane == 63) wsum[wv] = incl;
        __syncthreads();
        if (t < 16) {
            int s = wsum[t];
            int sc = s;
#pragma unroll
            for (int off = 1; off < 16; off <<= 1) {
                int u = __shfl_up(sc, off, 64);
                if (t >= off) sc += u;
            }
            wsum[t] = sc - s;          // exclusive prefix of wave sums
            if (t == 15) total_s = sc;
        }
        __syncthreads();
        if (i < N_NODES) rowptr[i + 1] = carry + wsum[wv] + incl;
        int tot = total_s;
        __syncthreads();
        carry += tot;
    }
}

__global__ void scatter_kernel(const int* __restrict__ ei, const int* __restrict__ rowptr,
                               int* __restrict__ fill, int* __restrict__ srcs) {
    int e = blockIdx.x * blockDim.x + threadIdx.x;
    if (e >= NUM_E) return;
    int dst = ei[NUM_E + e];
    int pos = rowptr[dst] + atomicAdd(&fill[dst], 1);
    srcs[pos] = ei[e];
}

// ---------------- prep: fp32 -> bf16 conversions ----------------
__global__ void cvt_x_kernel(const float* __restrict__ x, ushort_t* __restrict__ xb, long total4) {
    long i = (long)blockIdx.x * blockDim.x + threadIdx.x;
    if (i >= total4) return;
    float4 v = ((const float4*)x)[i];
    uint2 o;
    o.x = (uint_t)f2bf(v.x) | ((uint_t)f2bf(v.y) << 16);
    o.y = (uint_t)f2bf(v.z) | ((uint_t)f2bf(v.w) << 16);
    ((uint2*)xb)[i] = o;
}

// W [K][Ncols] fp32 -> Wt [Ncols][K] bf16
__global__ void prep_w_kernel(const float* __restrict__ W, ushort_t* __restrict__ Wt,
                              int K, int Ncols) {
    int i = blockIdx.x * blockDim.x + threadIdx.x;
    if (i >= K * Ncols) return;
    int k = i / Ncols, n = i % Ncols;
    Wt[n * K + k] = f2bf(W[i]);
}

// ---------------- bf16 MFMA GEMM: C[M,NFULL](bf16) = A[M,K](bf16) @ Bt[NFULL,K]^T ----------------
template<int K, int NFULL>
__global__ __launch_bounds__(256) void gemm_bf16_kernel(const ushort_t* __restrict__ A,
                                                        const ushort_t* __restrict__ Bt,
                                                        ushort_t* __restrict__ C) {
    __shared__ __align__(16) ushort_t As[128][40];
    __shared__ __align__(16) ushort_t Bs[64][40];
    __shared__ __align__(16) ushort_t Cs[4][32][64];
    int tid = threadIdx.x;
    int lane = tid & 63, w = tid >> 6;
    int row0 = blockIdx.x * 128, col0 = blockIdx.y * 64;
    int m_l = lane & 15, q = lane >> 4;

    f32x4 acc[2][4];
#pragma unroll
    for (int r = 0; r < 2; ++r)
#pragma unroll
        for (int c = 0; c < 4; ++c) acc[r][c] = (f32x4){0.f, 0.f, 0.f, 0.f};

    int ar = tid >> 1, ako = (tid & 1) * 16;
    int br = tid >> 2, bko = (tid & 3) * 8;

    for (int k0 = 0; k0 < K; k0 += 32) {
        uint4 a0 = make_uint4(0, 0, 0, 0), a1 = make_uint4(0, 0, 0, 0);
        int gr = row0 + ar;
        if (gr < N_NODES) {
            const ushort_t* ap = A + (long)gr * K + k0 + ako;
            a0 = *(const uint4*)ap;
            a1 = *(const uint4*)(ap + 8);
        }
        uint4 bv = *(const uint4*)(Bt + (long)(col0 + br) * K + k0 + bko);
        *(uint4*)&As[ar][ako] = a0;
        *(uint4*)&As[ar][ako + 8] = a1;
        *(uint4*)&Bs[br][bko] = bv;
        __syncthreads();

        bf16x8 af[2], bf[4];
#pragma unroll
        for (int r = 0; r < 2; ++r)
            af[r] = *(const bf16x8*)&As[w * 32 + r * 16 + m_l][q * 8];
#pragma unroll
        for (int c = 0; c < 4; ++c)
            bf[c] = *(const bf16x8*)&Bs[c * 16 + m_l][q * 8];
#pragma unroll
        for (int r = 0; r < 2; ++r)
#pragma unroll
            for (int c = 0; c < 4; ++c)
                acc[r][c] = __builtin_amdgcn_mfma_f32_16x16x32_bf16(af[r], bf[c], acc[r][c], 0, 0, 0);
        __syncthreads();
    }

#pragma unroll
    for (int r = 0; r < 2; ++r)
#pragma unroll
        for (int c = 0; c < 4; ++c)
#pragma unroll
            for (int i = 0; i < 4; ++i)
                Cs[w][r * 16 + q * 4 + i][c * 16 + m_l] = f2bf(acc[r][c][i]);
#pragma unroll
    for (int j = 0; j < 4; ++j) {
        int flat = j * 64 + lane;
        int lr = flat >> 3, ch = flat & 7;
        int gr = row0 + w * 32 + lr;
        if (gr < N_NODES)
            *(uint4*)(C + (long)gr * NFULL + col0 + ch * 8) = *(uint4*)&Cs[w][lr][ch * 8];
    }
}

// ---------------- per-node attention logits (bf16 h) ----------------
template<int H>
__global__ void logits_kernel(const ushort_t* __restrict__ h, const float* __restrict__ a_src,
                              const float* __restrict__ a_dst,
                              float* __restrict__ as_, float* __restrict__ ad_) {
    int i = blockIdx.x * blockDim.x + threadIdx.x;
    if (i >= N_NODES * H) return;
    int n = i / H, hh = i % H;
    const ushort_t* hp = h + (long)n * (H * 64) + hh * 64;
    const float* asp = a_src + hh * 64;
    const float* adp = a_dst + hh * 64;
    float s1 = 0.f, s2 = 0.f;
#pragma unroll
    for (int c = 0; c < 64; c += 8) {
        uint4 u = *(const uint4*)(hp + c);
        float f[8];
        f[0] = bflo(u.x); f[1] = bfhi(u.x);
        f[2] = bflo(u.y); f[3] = bfhi(u.y);
        f[4] = bflo(u.z); f[5] = bfhi(u.z);
        f[6] = bflo(u.w); f[7] = bfhi(u.w);
#pragma unroll
        for (int k = 0; k < 8; ++k) {
            s1 += f[k] * asp[c + k];
            s2 += f[k] * adp[c + k];
        }
    }
    as_[i] = s1;
    ad_[i] = s2;
}

// ---------------- GAT aggregation H=4: one wave/dst, 2 edges/iter (half-wave x 8ch) ----------------
__global__ __launch_bounds__(256) void agg4_kernel(const ushort_t* __restrict__ h,
                                                   const float* __restrict__ as_,
                                                   const float* __restrict__ ad_,
                                                   const int* __restrict__ rowptr,
                                                   const int* __restrict__ srcs,
                                                   const float* __restrict__ bias,
                                                   float* __restrict__ out) {
    __shared__ float alds[4][256];
    int lane = threadIdx.x & 63, w = threadIdx.x >> 6;
    int n = blockIdx.x * 4 + w;
    if (n >= N_NODES) return;
    int start = rowptr[n];
    int deg = rowptr[n + 1] - start;

    float4 adv = *(const float4*)(ad_ + n * 4);
    float ad4[4] = {adv.x, adv.y, adv.z, adv.w};

    // pass 1: per-lane online softmax; stage chunk-0 logits v into alds
    float mx[4] = {-1e30f, -1e30f, -1e30f, -1e30f};
    float dn[4] = {0.f, 0.f, 0.f, 0.f};
    int s0reg = 0;   // chunk-0 src (dummy = first edge for padded lanes)
    {
        float vst[4] = {-1e30f, -1e30f, -1e30f, -1e30f};
        if (deg > 0) s0reg = srcs[start + min(lane, deg - 1)];
        if (lane < deg) {
            float4 av = *(const float4*)(as_ + s0reg * 4);
            float vv[4] = {av.x + ad4[0], av.y + ad4[1], av.z + ad4[2], av.w + ad4[3]};
#pragma unroll
            for (int hh = 0; hh < 4; ++hh) {
                float v = vv[hh] > 0.f ? vv[hh] : 0.2f * vv[hh];
                vst[hh] = v; mx[hh] = v; dn[hh] = 1.f;
            }
        }
        *(float4*)&alds[w][lane * 4] = make_float4(vst[0], vst[1], vst[2], vst[3]);
        for (int j = lane + 64; j < deg; j += 64) {
            int s = srcs[start + j];
            float4 av = *(const float4*)(as_ + s * 4);
            float vv[4] = {av.x + ad4[0], av.y + ad4[1], av.z + ad4[2], av.w + ad4[3]};
#pragma unroll
            for (int hh = 0; hh < 4; ++hh) {
                float v = vv[hh] > 0.f ? vv[hh] : 0.2f * vv[hh];
                float mn = fmaxf(mx[hh], v);
                dn[hh] = dn[hh] * __expf(mx[hh] - mn) + __expf(v - mn);
                mx[hh] = mn;
            }
        }
    }
    // 2-phase reduce: global max, rescale once, sum
    float mloc[4] = {mx[0], mx[1], mx[2], mx[3]};
#pragma unroll
    for (int off = 1; off < 64; off <<= 1)
#pragma unroll
        for (int hh = 0; hh < 4; ++hh) mx[hh] = fmaxf(mx[hh], __shfl_xor(mx[hh], off, 64));
#pragma unroll
    for (int hh = 0; hh < 4; ++hh) dn[hh] *= __expf(mloc[hh] - mx[hh]);
#pragma unroll
    for (int off = 1; off < 64; off <<= 1)
#pragma unroll
        for (int hh = 0; hh < 4; ++hh) dn[hh] += __shfl_xor(dn[hh], off, 64);
    float inv[4];
#pragma unroll
    for (int hh = 0; hh < 4; ++hh) inv[hh] = dn[hh] > 0.f ? 1.f / dn[hh] : 0.f;

    // chunk-0 logits -> alphas in place (padded lanes: exp(-1e30-mx)->0)
    {
        float4 vv = *(const float4*)&alds[w][lane * 4];
        float4 al;
        al.x = __expf(vv.x - mx[0]) * inv[0];
        al.y = __expf(vv.y - mx[1]) * inv[1];
        al.z = __expf(vv.z - mx[2]) * inv[2];
        al.w = __expf(vv.w - mx[3]) * inv[3];
        *(float4*)&alds[w][lane * 4] = al;
    }

    // gather: half-wave per edge, 8 ch/lane, guard-free padded inner loop
    int half = lane >> 5, cl = lane & 31, hd = cl >> 3;
    float acc[8] = {0.f, 0.f, 0.f, 0.f, 0.f, 0.f, 0.f, 0.f};
    for (int chunk = 0; chunk < deg || chunk == 0; chunk += 64) {
        int s = s0reg;
        if (chunk > 0) {
            int j = chunk + lane;
            float4 al = make_float4(0.f, 0.f, 0.f, 0.f);
            s = srcs[start + min(j, deg - 1)];
            if (j < deg) {
                float4 av = *(const float4*)(as_ + s * 4);
                float vv[4] = {av.x + ad4[0], av.y + ad4[1], av.z + ad4[2], av.w + ad4[3]};
                float a4[4];
#pragma unroll
                for (int hh = 0; hh < 4; ++hh) {
                    float v = vv[hh] > 0.f ? vv[hh] : 0.2f * vv[hh];
                    a4[hh] = __expf(v - mx[hh]) * inv[hh];
                }
                al = make_float4(a4[0], a4[1], a4[2], a4[3]);
            }
            *(float4*)&alds[w][lane * 4] = al;
        }
        int cnt = min(64, deg - chunk);
        if (cnt < 0) cnt = 0;
        int cnt2 = (cnt + 1) & ~1;
#pragma unroll 2
        for (int e = 0; e < cnt2; e += 2) {
            int idx = e + half;
            int se = __shfl(s, idx, 64);
            float al = alds[w][idx * 4 + hd];
            const ushort_t* hr = h + (long)se * 256 + cl * 8;
            uint4 u = *(const uint4*)hr;
            acc[0] += al * bflo(u.x); acc[1] += al * bfhi(u.x);
            acc[2] += al * bflo(u.y); acc[3] += al * bfhi(u.y);
            acc[4] += al * bflo(u.z); acc[5] += al * bfhi(u.z);
            acc[6] += al * bflo(u.w); acc[7] += al * bfhi(u.w);
        }
        if (deg <= 64) break;
    }
    // combine the two half-wave edge streams
#pragma unroll
    for (int k = 0; k < 8; ++k) acc[k] += __shfl_xor(acc[k], 32, 64);
    if (half == 0) {
        int c0 = cl * 8;
        float4 b0 = *(const float4*)(bias + c0);
        float4 b1 = *(const float4*)(bias + c0 + 4);
        float4 o0, o1;
        o0.x = fmaxf(acc[0] + b0.x, 0.f); o0.y = fmaxf(acc[1] + b0.y, 0.f);
        o0.z = fmaxf(acc[2] + b0.z, 0.f); o0.w = fmaxf(acc[3] + b0.w, 0.f);
        o1.x = fmaxf(acc[4] + b1.x, 0.f); o1.y = fmaxf(acc[5] + b1.y, 0.f);
        o1.z = fmaxf(acc[6] + b1.z, 0.f); o1.w = fmaxf(acc[7] + b1.w, 0.f);
        *(float4*)(out + (long)n * 256 + c0) = o0;
        *(float4*)(out + (long)n * 256 + c0 + 4) = o1;
    }
}

// ---------------- GAT aggregation H=1: one wave/dst, 4 edges/iter (quarter-wave x 4ch) ----------------
__global__ __launch_bounds__(256) void agg1_kernel(const ushort_t* __restrict__ h,
                                                   const float* __restrict__ as_,
                                                   const float* __restrict__ ad_,
                                                   const int* __restrict__ rowptr,
                                                   const int* __restrict__ srcs,
                                                   const float* __restrict__ bias,
                                                   float* __restrict__ out) {
    __shared__ float alds1[4][64];
    int lane = threadIdx.x & 63, w = threadIdx.x >> 6;
    int n = blockIdx.x * 4 + w;
    if (n >= N_NODES) return;
    int start = rowptr[n];
    int deg = rowptr[n + 1] - start;
    float adn = ad_[n];

    float mx = -1e30f, dn = 0.f;
    int s0reg = 0;
    {
        float vst = -1e30f;
        if (deg > 0) s0reg = srcs[start + min(lane, deg - 1)];
        if (lane < deg) {
            float v = as_[s0reg] + adn;
            v = v > 0.f ? v : 0.2f * v;
            vst = v; mx = v; dn = 1.f;
        }
        alds1[w][lane] = vst;
        for (int j = lane + 64; j < deg; j += 64) {
            int s = srcs[start + j];
            float v = as_[s] + adn;
            v = v > 0.f ? v : 0.2f * v;
            float mn = fmaxf(mx, v);
            dn = dn * __expf(mx - mn) + __expf(v - mn);
            mx = mn;
        }
    }
    float mloc = mx;
#pragma unroll
    for (int off = 1; off < 64; off <<= 1) mx = fmaxf(mx, __shfl_xor(mx, off, 64));
    dn *= __expf(mloc - mx);
#pragma unroll
    for (int off = 1; off < 64; off <<= 1) dn += __shfl_xor(dn, off, 64);
    float inv = dn > 0.f ? 1.f / dn : 0.f;

    alds1[w][lane] = __expf(alds1[w][lane] - mx) * inv;

    int quarter = lane >> 4, cl = lane & 15;
    float acc[4] = {0.f, 0.f, 0.f, 0.f};
    for (int chunk = 0; chunk < deg || chunk == 0; chunk += 64) {
        int s = s0reg;
        if (chunk > 0) {
            int j = chunk + lane;
            float al = 0.f;
            s = srcs[start + min(j, deg - 1)];
            if (j < deg) {
                float v = as_[s] + adn;
                v = v > 0.f ? v : 0.2f * v;
                al = __expf(v - mx) * inv;
            }
            alds1[w][lane] = al;
        }
        int cnt = min(64, deg - chunk);
        if (cnt < 0) cnt = 0;
        int cnt2 = (cnt + 3) & ~3;
#pragma unroll 2
        for (int e = 0; e < cnt2; e += 4) {
            int idx = e + quarter;
            int se = __shfl(s, idx, 64);
            float al = alds1[w][idx];
            const ushort_t* hr = h + (long)se * 64 + cl * 4;
            uint2 u = *(const uint2*)hr;
            acc[0] += al * bflo(u.x); acc[1] += al * bfhi(u.x);
            acc[2] += al * bflo(u.y); acc[3] += al * bfhi(u.y);
        }
        if (deg <= 64) break;
    }
#pragma unroll
    for (int k = 0; k < 4; ++k) {
        acc[k] += __shfl_xor(acc[k], 16, 64);
        acc[k] += __shfl_xor(acc[k], 32, 64);
    }
    if (lane < 16) {
        int c0 = cl * 4;
        float4 bv = *(const float4*)(bias + c0);
        float4 o;
        o.x = fmaxf(acc[0] + bv.x, 0.f);
        o.y = fmaxf(acc[1] + bv.y, 0.f);
        o.z = fmaxf(acc[2] + bv.z, 0.f);
        o.w = fmaxf(acc[3] + bv.w, 0.f);
        *(float4*)(out + (long)n * 64 + c0) = o;
    }
}

// ---------------- BatchNorm ----------------
__global__ void bn_stats_kernel(const float* __restrict__ x, float* __restrict__ stats, int C) {
    int c = threadIdx.x;
    if (c >= C) return;
    float s = 0.f, s2 = 0.f;
    for (int n = blockIdx.x; n < N_NODES; n += gridDim.x) {
        float v = x[(long)n * C + c];
        s += v;
        s2 += v * v;
    }
    atomicAdd(&stats[c], s);
    atomicAdd(&stats[256 + c], s2);
}

__global__ void bn_apply_bf16_kernel(const float* __restrict__ x, ushort_t* __restrict__ xb,
                                     const float* __restrict__ stats,
                                     const float* __restrict__ g, const float* __restrict__ be,
                                     int C, long total) {
    long i = (long)blockIdx.x * blockDim.x + threadIdx.x;
    if (i >= total) return;
    int c = (int)(i % C);
    float mean = stats[c] * (1.f / N_NODES);
    float var = fmaxf(stats[256 + c] * (1.f / N_NODES) - mean * mean, 0.f);
    xb[i] = f2bf((x[i] - mean) * rsqrtf(var + EPS_BN) * g[c] + be[c]);
}

__global__ void bn_apply_f32_kernel(float* __restrict__ x, const float* __restrict__ stats,
                                    const float* __restrict__ g, const float* __restrict__ be,
                                    int C, long total) {
    long i = (long)blockIdx.x * blockDim.x + threadIdx.x;
    if (i >= total) return;
    int c = (int)(i % C);
    float mean = stats[c] * (1.f / N_NODES);
    float var = fmaxf(stats[256 + c] * (1.f / N_NODES) - mean * mean, 0.f);
    x[i] = (x[i] - mean) * rsqrtf(var + EPS_BN) * g[c] + be[c];
}

// ---------------- pool + FC ----------------
__global__ void batch_offsets_kernel(const int* __restrict__ batch, int* __restrict__ goff) {
    int g = threadIdx.x;
    if (g > NUM_GRAPHS) return;
    int lo = 0, hi = N_NODES;
    while (lo < hi) {
        int mid = (lo + hi) >> 1;
        if (batch[mid] < g) lo = mid + 1; else hi = mid;
    }
    goff[g] = lo;
}

__global__ __launch_bounds__(256) void pool2_kernel(const float* __restrict__ h,
                                                    const int* __restrict__ goff,
                                                    float* __restrict__ pooled) {
    int g = blockIdx.x;
    int c = threadIdx.x & 63;
    int ty = threadIdx.x >> 6;
    int s = goff[g], e = goff[g + 1];
    float sum = 0.f;
    for (int n = s + ty; n < e; n += 4) sum += h[(long)n * 64 + c];
    __shared__ float red[4][64];
    red[ty][c] = sum;
    __syncthreads();
    if (ty == 0) {
        float tot = red[0][c] + red[1][c] + red[2][c] + red[3][c];
        pooled[g * 64 + c] = tot / fmaxf((float)(e - s), 1.f);
    }
}

__global__ void fc_kernel(const float* __restrict__ pooled, const float* __restrict__ fcW,
                          const float* __restrict__ fcb, float* __restrict__ out) {
    int i = blockIdx.x * blockDim.x + threadIdx.x;
    if (i >= NUM_GRAPHS * 10) return;
    int g = i / 10, j = i % 10;
    float s = 0.f;
    for (int k = 0; k < 64; ++k) s += pooled[g * 64 + k] * fcW[k * 10 + j];
    out[i] = s + fcb[j];
}

extern "C" void kernel_launch(void* const* d_in, const int* in_sizes, int n_in,
                              void* d_out, int out_size, void* d_ws, size_t ws_size,
                              hipStream_t stream) {
    const float* x      = (const float*)d_in[0];
    const int*   ei     = (const int*)d_in[1];
    const int*   batch  = (const int*)d_in[2];
    const float* W1     = (const float*)d_in[3];
    const float* a_src1 = (const float*)d_in[4];
    const float* a_dst1 = (const float*)d_in[5];
    const float* b1     = (const float*)d_in[6];
    const float* g1     = (const float*)d_in[7];
    const float* be1    = (const float*)d_in[8];
    const float* W2     = (const float*)d_in[9];
    const float* a_src2 = (const float*)d_in[10];
    const float* a_dst2 = (const float*)d_in[11];
    const float* b2     = (const float*)d_in[12];
    const float* g2     = (const float*)d_in[13];
    const float* be2    = (const float*)d_in[14];
    const float* W3     = (const float*)d_in[15];
    const float* a_src3 = (const float*)d_in[16];
    const float* a_dst3 = (const float*)d_in[17];
    const float* b3     = (const float*)d_in[18];
    const float* g3     = (const float*)d_in[19];
    const float* be3    = (const float*)d_in[20];
    const float* fcW    = (const float*)d_in[21];
    const float* fcb    = (const float*)d_in[22];
    float* out = (float*)d_out;

    const size_t N = N_NODES, E = NUM_E;
    float*    bufB  = (float*)d_ws;                    // [N,256] fp32 agg output
    ushort_t* hbf   = (ushort_t*)(bufB + N * 256);     // [N,256] bf16 GEMM output
    ushort_t* ginp  = hbf + N * 256;                   // [N,256] bf16 GEMM input
    ushort_t* w1t   = ginp + N * 256;                  // [256][128]
    ushort_t* w2t   = w1t + 256 * 128;                 // [256][256]
    ushort_t* w3t   = w2t + 256 * 256;                 // [64][256]
    float*    as_   = (float*)(w3t + 64 * 256);        // [N,4]
    float*    ad_   = as_ + N * 4;                     // [N,4]
    int*      deg   = (int*)(ad_ + N * 4);             // [N]
    int*      rowptr= deg + N;                         // [N+1]
    int*      fill  = rowptr + (N + 1);                // [N]
    int*      srcs  = fill + N;                        // [E]
    float*    stats = (float*)(srcs + E);              // [512]
    float*    pooled= stats + 512;                     // [64*64]
    int*      goff  = (int*)(pooled + 64 * 64);        // [65]

    hipMemsetAsync(deg, 0, sizeof(int) * (N + (N + 1) + N), stream);
    hist_kernel<<<(NUM_E + 255) / 256, 256, 0, stream>>>(ei, deg);
    scan_kernel<<<1, 1024, 0, stream>>>(deg, rowptr);
    scatter_kernel<<<(NUM_E + 255) / 256, 256, 0, stream>>>(ei, rowptr, fill, srcs);
    batch_offsets_kernel<<<1, 128, 0, stream>>>(batch, goff);
    cvt_x_kernel<<<(N_NODES * 128 / 4 + 255) / 256, 256, 0, stream>>>(x, ginp, (long)N_NODES * 128 / 4);
    prep_w_kernel<<<(128 * 256 + 255) / 256, 256, 0, stream>>>(W1, w1t, 128, 256);
    prep_w_kernel<<<(256 * 256 + 255) / 256, 256, 0, stream>>>(W2, w2t, 256, 256);
    prep_w_kernel<<<(256 * 64 + 255) / 256, 256, 0, stream>>>(W3, w3t, 256, 64);

    const int GB = (N_NODES + 127) / 128;  // 391

    // ---- layer 1 ----
    gemm_bf16_kernel<128, 256><<<dim3(GB, 4), 256, 0, stream>>>(ginp, w1t, hbf);
    logits_kernel<4><<<(N_NODES * 4 + 255) / 256, 256, 0, stream>>>(hbf, a_src1, a_dst1, as_, ad_);
    agg4_kernel<<<(N_NODES + 3) / 4, 256, 0, stream>>>(hbf, as_, ad_, rowptr, srcs, b1, bufB);
    hipMemsetAsync(stats, 0, 512 * sizeof(float), stream);
    bn_stats_kernel<<<256, 256, 0, stream>>>(bufB, stats, 256);
    bn_apply_bf16_kernel<<<(N_NODES * 256 + 255) / 256, 256, 0, stream>>>(bufB, ginp, stats, g1, be1, 256, (long)N_NODES * 256);

    // ---- layer 2 ----
    gemm_bf16_kernel<256, 256><<<dim3(GB, 4), 256, 0, stream>>>(ginp, w2t, hbf);
    logits_kernel<4><<<(N_NODES * 4 + 255) / 256, 256, 0, stream>>>(hbf, a_src2, a_dst2, as_, ad_);
    agg4_kernel<<<(N_NODES + 3) / 4, 256, 0, stream>>>(hbf, as_, ad_, rowptr, srcs, b2, bufB);
    hipMemsetAsync(stats, 0, 512 * sizeof(float), stream);
    bn_stats_kernel<<<256, 256, 0, stream>>>(bufB, stats, 256);
    bn_apply_bf16_kernel<<<(N_NODES * 256 + 255) / 256, 256, 0, stream>>>(bufB, ginp, stats, g2, be2, 256, (long)N_NODES * 256);

    // ---- layer 3 ----
    gemm_bf16_kernel<256, 64><<<dim3(GB, 1), 256, 0, stream>>>(ginp, w3t, hbf);
    logits_kernel<1><<<(N_NODES + 255) / 256, 256, 0, stream>>>(hbf, a_src3, a_dst3, as_, ad_);
    agg1_kernel<<<(N_NODES + 3) / 4, 256, 0, stream>>>(hbf, as_, ad_, rowptr, srcs, b3, bufB);
    hipMemsetAsync(stats, 0, 512 * sizeof(float), stream);
    bn_stats_kernel<<<256, 64, 0, stream>>>(bufB, stats, 64);
    bn_apply_f32_kernel<<<(N_NODES * 64 + 255) / 256, 256, 0, stream>>>(bufB, stats, g3, be3, 64, (long)N_NODES * 64);

    // ---- pool + FC ----
    pool2_kernel<<<NUM_GRAPHS, 256, 0, stream>>>(bufB, goff, pooled);
    fc_kernel<<<3, 256, 0, stream>>>(pooled, fcW, fcb, out);
}

// Round 6
// 666.991 us; speedup vs baseline: 2.1736x; 1.1982x over previous
//
#include <hip/hip_runtime.h>
#include <hip/hip_bf16.h>

#define N_NODES 50000
#define NUM_E   800000
#define EPS_BN  1e-5f
#define NUM_GRAPHS 64

typedef __attribute__((ext_vector_type(8))) short bf16x8;
typedef __attribute__((ext_vector_type(4))) float f32x4;
typedef unsigned short ushort_t;
typedef unsigned int uint_t;

static __device__ __forceinline__ unsigned short f2bf(float f) {
    unsigned int u = __float_as_uint(f);
    u += 0x7fffu + ((u >> 16) & 1u);   // RNE
    return (unsigned short)(u >> 16);
}
static __device__ __forceinline__ float bflo(uint_t u) { return __uint_as_float(u << 16); }
static __device__ __forceinline__ float bfhi(uint_t u) { return __uint_as_float(u & 0xffff0000u); }

// ---------------- CSR build ----------------
__global__ void hist_kernel(const int* __restrict__ ei, int* __restrict__ deg) {
    int e = blockIdx.x * blockDim.x + threadIdx.x;
    if (e >= NUM_E) return;
    atomicAdd(&deg[ei[NUM_E + e]], 1);
}

// multi-block scan: local inclusive scan + block sums
__global__ void scan_local_kernel(const int* __restrict__ deg, int* __restrict__ rowptr,
                                  int* __restrict__ bsum) {
    __shared__ int ws[4];
    int b = blockIdx.x, t = threadIdx.x;
    int i = b * 256 + t;
    int lane = t & 63, wv = t >> 6;
    int v = (i < N_NODES) ? deg[i] : 0;
    int incl = v;
#pragma unroll
    for (int off = 1; off < 64; off <<= 1) {
        int u = __shfl_up(incl, off, 64);
        if (lane >= off) incl += u;
    }
    if (lane == 63) ws[wv] = incl;
    __syncthreads();
    if (t == 0) {
        int s = 0;
#pragma unroll
        for (int k = 0; k < 4; ++k) { int x = ws[k]; ws[k] = s; s += x; }
        bsum[b] = s;
    }
    __syncthreads();
    if (i < N_NODES) rowptr[i + 1] = ws[wv] + incl;
}

__global__ void scan_sums_kernel(int* __restrict__ bsum, int nb) {
    __shared__ int ws[4];
    int t = threadIdx.x;
    int lane = t & 63, wv = t >> 6;
    int v = (t < nb) ? bsum[t] : 0;
    int incl = v;
#pragma unroll
    for (int off = 1; off < 64; off <<= 1) {
        int u = __shfl_up(incl, off, 64);
        if (lane >= off) incl += u;
    }
    if (lane == 63) ws[wv] = incl;
    __syncthreads();
    if (t == 0) {
        int s = 0;
#pragma unroll
        for (int k = 0; k < 4; ++k) { int x = ws[k]; ws[k] = s; s += x; }
    }
    __syncthreads();
    if (t < nb) bsum[t] = ws[wv] + incl - v;   // exclusive
}

__global__ void scan_add_kernel(int* __restrict__ rowptr, const int* __restrict__ bsum) {
    int b = blockIdx.x, t = threadIdx.x;
    int i = b * 256 + t;
    if (i < N_NODES) rowptr[i + 1] += bsum[b];
    if (b == 0 && t == 0) rowptr[0] = 0;
}

__global__ void scatter_kernel(const int* __restrict__ ei, const int* __restrict__ rowptr,
                               int* __restrict__ fill, int* __restrict__ srcs) {
    int e = blockIdx.x * blockDim.x + threadIdx.x;
    if (e >= NUM_E) return;
    int dst = ei[NUM_E + e];
    int pos = rowptr[dst] + atomicAdd(&fill[dst], 1);
    srcs[pos] = ei[e];
}

// ---------------- weight prep (all 3 in one) ----------------
__global__ void prep_w_all(const float* __restrict__ W1, const float* __restrict__ W2,
                           const float* __restrict__ W3, ushort_t* __restrict__ w1t,
                           ushort_t* __restrict__ w2t, ushort_t* __restrict__ w3t) {
    int i = blockIdx.x * blockDim.x + threadIdx.x;
    const int S1 = 128 * 256, S2 = 256 * 256, S3 = 256 * 64;
    if (i < S1) {
        int k = i / 256, n = i % 256;
        w1t[n * 128 + k] = f2bf(W1[i]);
    } else if (i < S1 + S2) {
        int j = i - S1; int k = j / 256, n = j % 256;
        w2t[n * 256 + k] = f2bf(W2[j]);
    } else if (i < S1 + S2 + S3) {
        int j = i - S1 - S2; int k = j / 64, n = j % 64;
        w3t[n * 256 + k] = f2bf(W3[j]);
    }
}

// ---------------- fused GEMM: BN-affine(A fp32)->bf16 @ Bt^T -> h(bf16) + logits ----------------
// C[M,NFULL] = affine(A)[M,K] @ Bt[NFULL,K]^T ; block (bx,by) covers rows bx*128, cols by*64
// cols by*64.. are exactly head `by` -> epilogue computes full as_/ad_ for its rows.
template<int K, int NFULL>
__global__ __launch_bounds__(256) void gemm_fused_kernel(const float* __restrict__ A,
                                                         const ushort_t* __restrict__ Bt,
                                                         ushort_t* __restrict__ C,
                                                         const float* __restrict__ stats,
                                                         const float* __restrict__ g,
                                                         const float* __restrict__ be,
                                                         const float* __restrict__ a_src,
                                                         const float* __restrict__ a_dst,
                                                         float* __restrict__ as_,
                                                         float* __restrict__ ad_) {
    __shared__ __align__(16) ushort_t As[128][40];
    __shared__ __align__(16) ushort_t Bs[64][40];
    __shared__ __align__(16) ushort_t Cs[4][32][64];
    __shared__ __align__(16) float aff_a[K], aff_b[K];
    __shared__ float asrc_s[64], adst_s[64];
    int tid = threadIdx.x;
    int lane = tid & 63, w = tid >> 6;
    int row0 = blockIdx.x * 128, col0 = blockIdx.y * 64;
    int m_l = lane & 15, q = lane >> 4;

    // BN affine coefficients: A' = a[k]*A + b[k]  (identity if stats==null)
    for (int c = tid; c < K; c += 256) {
        float a = 1.f, b = 0.f;
        if (stats) {
            float m = stats[c] * (1.f / N_NODES);
            float var = fmaxf(stats[256 + c] * (1.f / N_NODES) - m * m, 0.f);
            float rs = rsqrtf(var + EPS_BN) * g[c];
            a = rs; b = be[c] - m * rs;
        }
        aff_a[c] = a; aff_b[c] = b;
    }
    if (tid < 64) {
        asrc_s[tid] = a_src[blockIdx.y * 64 + tid];
        adst_s[tid] = a_dst[blockIdx.y * 64 + tid];
    }
    __syncthreads();

    f32x4 acc[2][4];
#pragma unroll
    for (int r = 0; r < 2; ++r)
#pragma unroll
        for (int c = 0; c < 4; ++c) acc[r][c] = (f32x4){0.f, 0.f, 0.f, 0.f};

    int ar = tid >> 1, ako = (tid & 1) * 16;   // A stage: row, chan offset (16 ch/lane)
    int br = tid >> 2, bko = (tid & 3) * 8;    // B stage

    for (int k0 = 0; k0 < K; k0 += 32) {
        float v[16];
#pragma unroll
        for (int t = 0; t < 16; ++t) v[t] = 0.f;
        int gr = row0 + ar;
        if (gr < N_NODES) {
            const float* ap = A + (long)gr * K + k0 + ako;
#pragma unroll
            for (int t = 0; t < 4; ++t) {
                float4 f = *(const float4*)(ap + t * 4);
                v[t * 4 + 0] = f.x; v[t * 4 + 1] = f.y; v[t * 4 + 2] = f.z; v[t * 4 + 3] = f.w;
            }
        }
        uint_t ow[8];
#pragma unroll
        for (int t = 0; t < 8; ++t) {
            int k = ako + t * 2;
            float lo = v[t * 2] * aff_a[k0 + k] + aff_b[k0 + k];
            float hi = v[t * 2 + 1] * aff_a[k0 + k + 1] + aff_b[k0 + k + 1];
            ow[t] = (uint_t)f2bf(lo) | ((uint_t)f2bf(hi) << 16);
        }
        uint4 bv = *(const uint4*)(Bt + (long)(col0 + br) * K + k0 + bko);
        *(uint4*)&As[ar][ako] = make_uint4(ow[0], ow[1], ow[2], ow[3]);
        *(uint4*)&As[ar][ako + 8] = make_uint4(ow[4], ow[5], ow[6], ow[7]);
        *(uint4*)&Bs[br][bko] = bv;
        __syncthreads();

        bf16x8 af[2], bf[4];
#pragma unroll
        for (int r = 0; r < 2; ++r)
            af[r] = *(const bf16x8*)&As[w * 32 + r * 16 + m_l][q * 8];
#pragma unroll
        for (int c = 0; c < 4; ++c)
            bf[c] = *(const bf16x8*)&Bs[c * 16 + m_l][q * 8];
#pragma unroll
        for (int r = 0; r < 2; ++r)
#pragma unroll
            for (int c = 0; c < 4; ++c)
                acc[r][c] = __builtin_amdgcn_mfma_f32_16x16x32_bf16(af[r], bf[c], acc[r][c], 0, 0, 0);
        __syncthreads();
    }

    // epilogue: regs -> LDS transpose -> coalesced stores + fused per-head logits
#pragma unroll
    for (int r = 0; r < 2; ++r)
#pragma unroll
        for (int c = 0; c < 4; ++c)
#pragma unroll
            for (int i = 0; i < 4; ++i)
                Cs[w][r * 16 + q * 4 + i][c * 16 + m_l] = f2bf(acc[r][c][i]);
    // same-wave LDS RAW: in-order DS pipe
    const int H = NFULL / 64;
#pragma unroll
    for (int j = 0; j < 4; ++j) {
        int flat = j * 64 + lane;
        int lr = flat >> 3, chg = flat & 7;
        int gr = row0 + w * 32 + lr;
        uint4 u = *(uint4*)&Cs[w][lr][chg * 8];
        float f0 = bflo(u.x), f1 = bfhi(u.x), f2 = bflo(u.y), f3 = bfhi(u.y);
        float f4 = bflo(u.z), f5 = bfhi(u.z), f6 = bflo(u.w), f7 = bfhi(u.w);
        int cb = chg * 8;
        float s1 = f0 * asrc_s[cb] + f1 * asrc_s[cb + 1] + f2 * asrc_s[cb + 2] + f3 * asrc_s[cb + 3]
                 + f4 * asrc_s[cb + 4] + f5 * asrc_s[cb + 5] + f6 * asrc_s[cb + 6] + f7 * asrc_s[cb + 7];
        float s2 = f0 * adst_s[cb] + f1 * adst_s[cb + 1] + f2 * adst_s[cb + 2] + f3 * adst_s[cb + 3]
                 + f4 * adst_s[cb + 4] + f5 * adst_s[cb + 5] + f6 * adst_s[cb + 6] + f7 * adst_s[cb + 7];
#pragma unroll
        for (int o = 1; o < 8; o <<= 1) {
            s1 += __shfl_xor(s1, o, 64);
            s2 += __shfl_xor(s2, o, 64);
        }
        if (gr < N_NODES) {
            *(uint4*)(C + (long)gr * NFULL + col0 + chg * 8) = u;
            if ((lane & 7) == 0) {
                as_[gr * H + blockIdx.y] = s1;
                ad_[gr * H + blockIdx.y] = s2;
            }
        }
    }
}

// ---------------- GAT aggregation H=4: one wave/dst, half-wave x 8ch ----------------
__global__ __launch_bounds__(256) void agg4_kernel(const ushort_t* __restrict__ h,
                                                   const float* __restrict__ as_,
                                                   const float* __restrict__ ad_,
                                                   const int* __restrict__ rowptr,
                                                   const int* __restrict__ srcs,
                                                   const float* __restrict__ bias,
                                                   float* __restrict__ out) {
    __shared__ float alds[4][256];
    int lane = threadIdx.x & 63, w = threadIdx.x >> 6;
    int n = blockIdx.x * 4 + w;
    if (n >= N_NODES) return;
    int start = rowptr[n];
    int deg = rowptr[n + 1] - start;

    float4 adv = *(const float4*)(ad_ + n * 4);
    float ad4[4] = {adv.x, adv.y, adv.z, adv.w};

    float mx[4] = {-1e30f, -1e30f, -1e30f, -1e30f};
    float dn[4] = {0.f, 0.f, 0.f, 0.f};
    int s0reg = 0;
    {
        float vst[4] = {-1e30f, -1e30f, -1e30f, -1e30f};
        if (deg > 0) s0reg = srcs[start + min(lane, deg - 1)];
        if (lane < deg) {
            float4 av = *(const float4*)(as_ + s0reg * 4);
            float vv[4] = {av.x + ad4[0], av.y + ad4[1], av.z + ad4[2], av.w + ad4[3]};
#pragma unroll
            for (int hh = 0; hh < 4; ++hh) {
                float v = vv[hh] > 0.f ? vv[hh] : 0.2f * vv[hh];
                vst[hh] = v; mx[hh] = v; dn[hh] = 1.f;
            }
        }
        *(float4*)&alds[w][lane * 4] = make_float4(vst[0], vst[1], vst[2], vst[3]);
        for (int j = lane + 64; j < deg; j += 64) {
            int s = srcs[start + j];
            float4 av = *(const float4*)(as_ + s * 4);
            float vv[4] = {av.x + ad4[0], av.y + ad4[1], av.z + ad4[2], av.w + ad4[3]};
#pragma unroll
            for (int hh = 0; hh < 4; ++hh) {
                float v = vv[hh] > 0.f ? vv[hh] : 0.2f * vv[hh];
                float mn = fmaxf(mx[hh], v);
                dn[hh] = dn[hh] * __expf(mx[hh] - mn) + __expf(v - mn);
                mx[hh] = mn;
            }
        }
    }
    float mloc[4] = {mx[0], mx[1], mx[2], mx[3]};
#pragma unroll
    for (int off = 1; off < 64; off <<= 1)
#pragma unroll
        for (int hh = 0; hh < 4; ++hh) mx[hh] = fmaxf(mx[hh], __shfl_xor(mx[hh], off, 64));
#pragma unroll
    for (int hh = 0; hh < 4; ++hh) dn[hh] *= __expf(mloc[hh] - mx[hh]);
#pragma unroll
    for (int off = 1; off < 64; off <<= 1)
#pragma unroll
        for (int hh = 0; hh < 4; ++hh) dn[hh] += __shfl_xor(dn[hh], off, 64);
    float inv[4];
#pragma unroll
    for (int hh = 0; hh < 4; ++hh) inv[hh] = dn[hh] > 0.f ? 1.f / dn[hh] : 0.f;

    {
        float4 vv = *(const float4*)&alds[w][lane * 4];
        float4 al;
        al.x = __expf(vv.x - mx[0]) * inv[0];
        al.y = __expf(vv.y - mx[1]) * inv[1];
        al.z = __expf(vv.z - mx[2]) * inv[2];
        al.w = __expf(vv.w - mx[3]) * inv[3];
        *(float4*)&alds[w][lane * 4] = al;
    }

    int half = lane >> 5, cl = lane & 31, hd = cl >> 3;
    float acc[8] = {0.f, 0.f, 0.f, 0.f, 0.f, 0.f, 0.f, 0.f};
    for (int chunk = 0; chunk < deg || chunk == 0; chunk += 64) {
        int s = s0reg;
        if (chunk > 0) {
            int j = chunk + lane;
            float4 al = make_float4(0.f, 0.f, 0.f, 0.f);
            s = srcs[start + min(j, deg - 1)];
            if (j < deg) {
                float4 av = *(const float4*)(as_ + s * 4);
                float vv[4] = {av.x + ad4[0], av.y + ad4[1], av.z + ad4[2], av.w + ad4[3]};
                float a4[4];
#pragma unroll
                for (int hh = 0; hh < 4; ++hh) {
                    float v = vv[hh] > 0.f ? vv[hh] : 0.2f * vv[hh];
                    a4[hh] = __expf(v - mx[hh]) * inv[hh];
                }
                al = make_float4(a4[0], a4[1], a4[2], a4[3]);
            }
            *(float4*)&alds[w][lane * 4] = al;
        }
        int cnt = min(64, deg - chunk);
        if (cnt < 0) cnt = 0;
        int cnt2 = (cnt + 1) & ~1;
#pragma unroll 4
        for (int e = 0; e < cnt2; e += 2) {
            int idx = e + half;
            int se = __shfl(s, idx, 64);
            float al = alds[w][idx * 4 + hd];
            const ushort_t* hr = h + (long)se * 256 + cl * 8;
            uint4 u = *(const uint4*)hr;
            acc[0] += al * bflo(u.x); acc[1] += al * bfhi(u.x);
            acc[2] += al * bflo(u.y); acc[3] += al * bfhi(u.y);
            acc[4] += al * bflo(u.z); acc[5] += al * bfhi(u.z);
            acc[6] += al * bflo(u.w); acc[7] += al * bfhi(u.w);
        }
        if (deg <= 64) break;
    }
#pragma unroll
    for (int k = 0; k < 8; ++k) acc[k] += __shfl_xor(acc[k], 32, 64);
    if (half == 0) {
        int c0 = cl * 8;
        float4 b0 = *(const float4*)(bias + c0);
        float4 b1 = *(const float4*)(bias + c0 + 4);
        float4 o0, o1;
        o0.x = fmaxf(acc[0] + b0.x, 0.f); o0.y = fmaxf(acc[1] + b0.y, 0.f);
        o0.z = fmaxf(acc[2] + b0.z, 0.f); o0.w = fmaxf(acc[3] + b0.w, 0.f);
        o1.x = fmaxf(acc[4] + b1.x, 0.f); o1.y = fmaxf(acc[5] + b1.y, 0.f);
        o1.z = fmaxf(acc[6] + b1.z, 0.f); o1.w = fmaxf(acc[7] + b1.w, 0.f);
        *(float4*)(out + (long)n * 256 + c0) = o0;
        *(float4*)(out + (long)n * 256 + c0 + 4) = o1;
    }
}

// ---------------- GAT aggregation H=1: one wave/dst, 8 lanes/edge x 8ch ----------------
__global__ __launch_bounds__(256) void agg1_kernel(const ushort_t* __restrict__ h,
                                                   const float* __restrict__ as_,
                                                   const float* __restrict__ ad_,
                                                   const int* __restrict__ rowptr,
                                                   const int* __restrict__ srcs,
                                                   const float* __restrict__ bias,
                                                   float* __restrict__ out) {
    __shared__ float alds1[4][64];
    int lane = threadIdx.x & 63, w = threadIdx.x >> 6;
    int n = blockIdx.x * 4 + w;
    if (n >= N_NODES) return;
    int start = rowptr[n];
    int deg = rowptr[n + 1] - start;
    float adn = ad_[n];

    float mx = -1e30f, dn = 0.f;
    int s0reg = 0;
    {
        float vst = -1e30f;
        if (deg > 0) s0reg = srcs[start + min(lane, deg - 1)];
        if (lane < deg) {
            float v = as_[s0reg] + adn;
            v = v > 0.f ? v : 0.2f * v;
            vst = v; mx = v; dn = 1.f;
        }
        alds1[w][lane] = vst;
        for (int j = lane + 64; j < deg; j += 64) {
            int s = srcs[start + j];
            float v = as_[s] + adn;
            v = v > 0.f ? v : 0.2f * v;
            float mn = fmaxf(mx, v);
            dn = dn * __expf(mx - mn) + __expf(v - mn);
            mx = mn;
        }
    }
    float mloc = mx;
#pragma unroll
    for (int off = 1; off < 64; off <<= 1) mx = fmaxf(mx, __shfl_xor(mx, off, 64));
    dn *= __expf(mloc - mx);
#pragma unroll
    for (int off = 1; off < 64; off <<= 1) dn += __shfl_xor(dn, off, 64);
    float inv = dn > 0.f ? 1.f / dn : 0.f;

    alds1[w][lane] = __expf(alds1[w][lane] - mx) * inv;

    int eg = lane >> 3, cl = lane & 7;
    float acc[8] = {0.f, 0.f, 0.f, 0.f, 0.f, 0.f, 0.f, 0.f};
    for (int chunk = 0; chunk < deg || chunk == 0; chunk += 64) {
        int s = s0reg;
        if (chunk > 0) {
            int j = chunk + lane;
            float al = 0.f;
            s = srcs[start + min(j, deg - 1)];
            if (j < deg) {
                float v = as_[s] + adn;
                v = v > 0.f ? v : 0.2f * v;
                al = __expf(v - mx) * inv;
            }
            alds1[w][lane] = al;
        }
        int cnt = min(64, deg - chunk);
        if (cnt < 0) cnt = 0;
        int cnt8 = (cnt + 7) & ~7;
#pragma unroll 2
        for (int e = 0; e < cnt8; e += 8) {
            int idx = e + eg;
            int se = __shfl(s, idx, 64);
            float al = alds1[w][idx];
            const ushort_t* hr = h + (long)se * 64 + cl * 8;
            uint4 u = *(const uint4*)hr;
            acc[0] += al * bflo(u.x); acc[1] += al * bfhi(u.x);
            acc[2] += al * bflo(u.y); acc[3] += al * bfhi(u.y);
            acc[4] += al * bflo(u.z); acc[5] += al * bfhi(u.z);
            acc[6] += al * bflo(u.w); acc[7] += al * bfhi(u.w);
        }
        if (deg <= 64) break;
    }
#pragma unroll
    for (int k = 0; k < 8; ++k) {
        acc[k] += __shfl_xor(acc[k], 8, 64);
        acc[k] += __shfl_xor(acc[k], 16, 64);
        acc[k] += __shfl_xor(acc[k], 32, 64);
    }
    if (lane < 8) {
        int c0 = cl * 8;
        float4 b0 = *(const float4*)(bias + c0);
        float4 b1 = *(const float4*)(bias + c0 + 4);
        float4 o0, o1;
        o0.x = fmaxf(acc[0] + b0.x, 0.f); o0.y = fmaxf(acc[1] + b0.y, 0.f);
        o0.z = fmaxf(acc[2] + b0.z, 0.f); o0.w = fmaxf(acc[3] + b0.w, 0.f);
        o1.x = fmaxf(acc[4] + b1.x, 0.f); o1.y = fmaxf(acc[5] + b1.y, 0.f);
        o1.z = fmaxf(acc[6] + b1.z, 0.f); o1.w = fmaxf(acc[7] + b1.w, 0.f);
        *(float4*)(out + (long)n * 64 + c0) = o0;
        *(float4*)(out + (long)n * 64 + c0 + 4) = o1;
    }
}

// ---------------- BatchNorm stats ----------------
__global__ void bn_stats_kernel(const float* __restrict__ x, float* __restrict__ stats, int C) {
    int c = threadIdx.x;
    if (c >= C) return;
    float s = 0.f, s2 = 0.f;
    for (int n = blockIdx.x; n < N_NODES; n += gridDim.x) {
        float v = x[(long)n * C + c];
        s += v;
        s2 += v * v;
    }
    atomicAdd(&stats[c], s);
    atomicAdd(&stats[256 + c], s2);
}

// ---------------- pool (BN affine commutes with mean) + FC ----------------
__global__ void batch_offsets_kernel(const int* __restrict__ batch, int* __restrict__ goff) {
    int g = threadIdx.x;
    if (g > NUM_GRAPHS) return;
    int lo = 0, hi = N_NODES;
    while (lo < hi) {
        int mid = (lo + hi) >> 1;
        if (batch[mid] < g) lo = mid + 1; else hi = mid;
    }
    goff[g] = lo;
}

__global__ __launch_bounds__(256) void pool2_kernel(const float* __restrict__ h,
                                                    const int* __restrict__ goff,
                                                    const float* __restrict__ stats,
                                                    const float* __restrict__ g3,
                                                    const float* __restrict__ be3,
                                                    float* __restrict__ pooled) {
    int g = blockIdx.x;
    int c = threadIdx.x & 63;
    int ty = threadIdx.x >> 6;
    int s = goff[g], e = goff[g + 1];
    float sum = 0.f;
    for (int n = s + ty; n < e; n += 4) sum += h[(long)n * 64 + c];
    __shared__ float red[4][64];
    red[ty][c] = sum;
    __syncthreads();
    if (ty == 0) {
        float tot = red[0][c] + red[1][c] + red[2][c] + red[3][c];
        float v = tot / fmaxf((float)(e - s), 1.f);
        float m = stats[c] * (1.f / N_NODES);
        float var = fmaxf(stats[256 + c] * (1.f / N_NODES) - m * m, 0.f);
        pooled[g * 64 + c] = (v - m) * rsqrtf(var + EPS_BN) * g3[c] + be3[c];
    }
}

__global__ void fc_kernel(const float* __restrict__ pooled, const float* __restrict__ fcW,
                          const float* __restrict__ fcb, float* __restrict__ out) {
    int i = blockIdx.x * blockDim.x + threadIdx.x;
    if (i >= NUM_GRAPHS * 10) return;
    int g = i / 10, j = i % 10;
    float s = 0.f;
    for (int k = 0; k < 64; ++k) s += pooled[g * 64 + k] * fcW[k * 10 + j];
    out[i] = s + fcb[j];
}

extern "C" void kernel_launch(void* const* d_in, const int* in_sizes, int n_in,
                              void* d_out, int out_size, void* d_ws, size_t ws_size,
                              hipStream_t stream) {
    const float* x      = (const float*)d_in[0];
    const int*   ei     = (const int*)d_in[1];
    const int*   batch  = (const int*)d_in[2];
    const float* W1     = (const float*)d_in[3];
    const float* a_src1 = (const float*)d_in[4];
    const float* a_dst1 = (const float*)d_in[5];
    const float* b1     = (const float*)d_in[6];
    const float* g1     = (const float*)d_in[7];
    const float* be1    = (const float*)d_in[8];
    const float* W2     = (const float*)d_in[9];
    const float* a_src2 = (const float*)d_in[10];
    const float* a_dst2 = (const float*)d_in[11];
    const float* b2     = (const float*)d_in[12];
    const float* g2     = (const float*)d_in[13];
    const float* be2    = (const float*)d_in[14];
    const float* W3     = (const float*)d_in[15];
    const float* a_src3 = (const float*)d_in[16];
    const float* a_dst3 = (const float*)d_in[17];
    const float* b3     = (const float*)d_in[18];
    const float* g3     = (const float*)d_in[19];
    const float* be3    = (const float*)d_in[20];
    const float* fcW    = (const float*)d_in[21];
    const float* fcb    = (const float*)d_in[22];
    float* out = (float*)d_out;

    const size_t N = N_NODES, E = NUM_E;
    float*    bufB   = (float*)d_ws;                    // [N,256] fp32 agg output
    ushort_t* hbf    = (ushort_t*)(bufB + N * 256);     // [N,256] bf16 GEMM output
    ushort_t* w1t    = hbf + N * 256;                   // [256][128]
    ushort_t* w2t    = w1t + 256 * 128;                 // [256][256]
    ushort_t* w3t    = w2t + 256 * 256;                 // [64][256]
    float*    as_    = (float*)(w3t + 64 * 256 + 128);  // [N,4] (pad keeps 16B align)
    float*    ad_    = as_ + N * 4;                     // [N,4]
    // zero-init region (single memset): deg[N], fill[N], statsA/B/C[512 each]
    int*      deg    = (int*)(ad_ + N * 4);             // [N]
    int*      fill   = deg + N;                         // [N]
    float*    statsA = (float*)(fill + N);              // [512]
    float*    statsB = statsA + 512;                    // [512]
    float*    statsC = statsB + 512;                    // [512]
    int*      rowptr = (int*)(statsC + 512);            // [N+1]
    int*      srcs   = rowptr + (N + 1);                // [E]
    int*      bsum   = srcs + E;                        // [256]
    float*    pooled = (float*)(bsum + 256);            // [64*64]
    int*      goff   = (int*)(pooled + 64 * 64);        // [65]

    const int NB = (N_NODES + 255) / 256;  // 196

    // ---- CSR + offsets + weight prep ----
    hipMemsetAsync(deg, 0, sizeof(int) * (2 * N + 3 * 512), stream);
    hist_kernel<<<(NUM_E + 255) / 256, 256, 0, stream>>>(ei, deg);
    scan_local_kernel<<<NB, 256, 0, stream>>>(deg, rowptr, bsum);
    scan_sums_kernel<<<1, 256, 0, stream>>>(bsum, NB);
    scan_add_kernel<<<NB, 256, 0, stream>>>(rowptr, bsum);
    scatter_kernel<<<(NUM_E + 255) / 256, 256, 0, stream>>>(ei, rowptr, fill, srcs);
    batch_offsets_kernel<<<1, 128, 0, stream>>>(batch, goff);
    prep_w_all<<<(128 * 256 + 256 * 256 + 256 * 64 + 255) / 256, 256, 0, stream>>>(W1, W2, W3, w1t, w2t, w3t);

    const int GB = (N_NODES + 127) / 128;  // 391

    // ---- layer 1: A = x (identity affine), fused logits ----
    gemm_fused_kernel<128, 256><<<dim3(GB, 4), 256, 0, stream>>>(
        x, w1t, hbf, nullptr, nullptr, nullptr, a_src1, a_dst1, as_, ad_);
    agg4_kernel<<<(N_NODES + 3) / 4, 256, 0, stream>>>(hbf, as_, ad_, rowptr, srcs, b1, bufB);
    bn_stats_kernel<<<256, 256, 0, stream>>>(bufB, statsA, 256);

    // ---- layer 2: A = bufB with BN(statsA) affine fused ----
    gemm_fused_kernel<256, 256><<<dim3(GB, 4), 256, 0, stream>>>(
        bufB, w2t, hbf, statsA, g1, be1, a_src2, a_dst2, as_, ad_);
    agg4_kernel<<<(N_NODES + 3) / 4, 256, 0, stream>>>(hbf, as_, ad_, rowptr, srcs, b2, bufB);
    bn_stats_kernel<<<256, 256, 0, stream>>>(bufB, statsB, 256);

    // ---- layer 3: A = bufB with BN(statsB) affine fused ----
    gemm_fused_kernel<256, 64><<<dim3(GB, 1), 256, 0, stream>>>(
        bufB, w3t, hbf, statsB, g2, be2, a_src3, a_dst3, as_, ad_);
    agg1_kernel<<<(N_NODES + 3) / 4, 256, 0, stream>>>(hbf, as_, ad_, rowptr, srcs, b3, bufB);
    bn_stats_kernel<<<256, 64, 0, stream>>>(bufB, statsC, 64);

    // ---- pool (BN3 affine fused) + FC ----
    pool2_kernel<<<NUM_GRAPHS, 256, 0, stream>>>(bufB, goff, statsC, g3, be3, pooled);
    fc_kernel<<<3, 256, 0, stream>>>(pooled, fcW, fcb, out);
}

// Round 7
// 518.844 us; speedup vs baseline: 2.7942x; 1.2855x over previous
//
#include <hip/hip_runtime.h>
#include <hip/hip_bf16.h>

#define N_NODES 50000
#define NUM_E   800000
#define EPS_BN  1e-5f
#define NUM_GRAPHS 64

typedef __attribute__((ext_vector_type(8))) short bf16x8;
typedef __attribute__((ext_vector_type(4))) float f32x4;
typedef unsigned short ushort_t;
typedef unsigned int uint_t;

static __device__ __forceinline__ unsigned short f2bf(float f) {
    unsigned int u = __float_as_uint(f);
    u += 0x7fffu + ((u >> 16) & 1u);   // RNE
    return (unsigned short)(u >> 16);
}
static __device__ __forceinline__ float bflo(uint_t u) { return __uint_as_float(u << 16); }
static __device__ __forceinline__ float bfhi(uint_t u) { return __uint_as_float(u & 0xffff0000u); }

// ---------------- CSR build ----------------
__global__ void hist_kernel(const int* __restrict__ ei, int* __restrict__ deg) {
    int e = blockIdx.x * blockDim.x + threadIdx.x;
    if (e >= NUM_E) return;
    atomicAdd(&deg[ei[NUM_E + e]], 1);
}

__global__ void scan_local_kernel(const int* __restrict__ deg, int* __restrict__ rowptr,
                                  int* __restrict__ bsum) {
    __shared__ int ws[4];
    int b = blockIdx.x, t = threadIdx.x;
    int i = b * 256 + t;
    int lane = t & 63, wv = t >> 6;
    int v = (i < N_NODES) ? deg[i] : 0;
    int incl = v;
#pragma unroll
    for (int off = 1; off < 64; off <<= 1) {
        int u = __shfl_up(incl, off, 64);
        if (lane >= off) incl += u;
    }
    if (lane == 63) ws[wv] = incl;
    __syncthreads();
    if (t == 0) {
        int s = 0;
#pragma unroll
        for (int k = 0; k < 4; ++k) { int x = ws[k]; ws[k] = s; s += x; }
        bsum[b] = s;
    }
    __syncthreads();
    if (i < N_NODES) rowptr[i + 1] = ws[wv] + incl;
}

__global__ void scan_sums_kernel(int* __restrict__ bsum, int nb) {
    __shared__ int ws[4];
    int t = threadIdx.x;
    int lane = t & 63, wv = t >> 6;
    int v = (t < nb) ? bsum[t] : 0;
    int incl = v;
#pragma unroll
    for (int off = 1; off < 64; off <<= 1) {
        int u = __shfl_up(incl, off, 64);
        if (lane >= off) incl += u;
    }
    if (lane == 63) ws[wv] = incl;
    __syncthreads();
    if (t == 0) {
        int s = 0;
#pragma unroll
        for (int k = 0; k < 4; ++k) { int x = ws[k]; ws[k] = s; s += x; }
    }
    __syncthreads();
    if (t < nb) bsum[t] = ws[wv] + incl - v;   // exclusive
}

__global__ void scan_add_kernel(int* __restrict__ rowptr, const int* __restrict__ bsum) {
    int b = blockIdx.x, t = threadIdx.x;
    int i = b * 256 + t;
    if (i < N_NODES) rowptr[i + 1] += bsum[b];
    if (b == 0 && t == 0) rowptr[0] = 0;
}

__global__ void scatter_kernel(const int* __restrict__ ei, const int* __restrict__ rowptr,
                               int* __restrict__ fill, int* __restrict__ srcs) {
    int e = blockIdx.x * blockDim.x + threadIdx.x;
    if (e >= NUM_E) return;
    int dst = ei[NUM_E + e];
    int pos = rowptr[dst] + atomicAdd(&fill[dst], 1);
    srcs[pos] = ei[e];
}

// ---------------- weight prep ----------------
__global__ void prep_w_all(const float* __restrict__ W1, const float* __restrict__ W2,
                           const float* __restrict__ W3, ushort_t* __restrict__ w1t,
                           ushort_t* __restrict__ w2t, ushort_t* __restrict__ w3t) {
    int i = blockIdx.x * blockDim.x + threadIdx.x;
    const int S1 = 128 * 256, S2 = 256 * 256, S3 = 256 * 64;
    if (i < S1) {
        int k = i / 256, n = i % 256;
        w1t[n * 128 + k] = f2bf(W1[i]);
    } else if (i < S1 + S2) {
        int j = i - S1; int k = j / 256, n = j % 256;
        w2t[n * 256 + k] = f2bf(W2[j]);
    } else if (i < S1 + S2 + S3) {
        int j = i - S1 - S2; int k = j / 64, n = j % 64;
        w3t[n * 256 + k] = f2bf(W3[j]);
    }
}

// ---------------- fused GEMM: BN-affine(A)->bf16 @ Bt^T -> h(bf16) + per-head logits ----------------
template<int K, int NFULL, bool ABF16>
__global__ __launch_bounds__(256) void gemm_fused_kernel(const void* __restrict__ Araw,
                                                         const ushort_t* __restrict__ Bt,
                                                         ushort_t* __restrict__ C,
                                                         const float* __restrict__ stats,
                                                         const float* __restrict__ g,
                                                         const float* __restrict__ be,
                                                         const float* __restrict__ a_src,
                                                         const float* __restrict__ a_dst,
                                                         float* __restrict__ as_,
                                                         float* __restrict__ ad_) {
    __shared__ __align__(16) ushort_t As[128][40];
    __shared__ __align__(16) ushort_t Bs[64][40];
    __shared__ __align__(16) ushort_t Cs[4][32][64];
    __shared__ __align__(16) float aff_a[K], aff_b[K];
    __shared__ float asrc_s[64], adst_s[64];
    int tid = threadIdx.x;
    int lane = tid & 63, w = tid >> 6;
    int row0 = blockIdx.x * 128, col0 = blockIdx.y * 64;
    int m_l = lane & 15, q = lane >> 4;

    for (int c = tid; c < K; c += 256) {
        float a = 1.f, b = 0.f;
        if (stats) {
            float m = stats[c] * (1.f / N_NODES);
            float var = fmaxf(stats[256 + c] * (1.f / N_NODES) - m * m, 0.f);
            float rs = rsqrtf(var + EPS_BN) * g[c];
            a = rs; b = be[c] - m * rs;
        }
        aff_a[c] = a; aff_b[c] = b;
    }
    if (tid < 64) {
        asrc_s[tid] = a_src[blockIdx.y * 64 + tid];
        adst_s[tid] = a_dst[blockIdx.y * 64 + tid];
    }
    __syncthreads();

    f32x4 acc[2][4];
#pragma unroll
    for (int r = 0; r < 2; ++r)
#pragma unroll
        for (int c = 0; c < 4; ++c) acc[r][c] = (f32x4){0.f, 0.f, 0.f, 0.f};

    int ar = tid >> 1, ako = (tid & 1) * 16;
    int br = tid >> 2, bko = (tid & 3) * 8;

    for (int k0 = 0; k0 < K; k0 += 32) {
        uint_t ow[8];
        int gr = row0 + ar;
        if constexpr (ABF16) {
            const ushort_t* A = (const ushort_t*)Araw;
            uint4 u0 = make_uint4(0, 0, 0, 0), u1 = make_uint4(0, 0, 0, 0);
            if (gr < N_NODES) {
                const ushort_t* ap = A + (long)gr * K + k0 + ako;
                u0 = *(const uint4*)ap;
                u1 = *(const uint4*)(ap + 8);
            }
            uint_t uu[8] = {u0.x, u0.y, u0.z, u0.w, u1.x, u1.y, u1.z, u1.w};
#pragma unroll
            for (int t = 0; t < 8; ++t) {
                int k = k0 + ako + t * 2;
                float lo = bflo(uu[t]) * aff_a[k] + aff_b[k];
                float hi = bfhi(uu[t]) * aff_a[k + 1] + aff_b[k + 1];
                ow[t] = (uint_t)f2bf(lo) | ((uint_t)f2bf(hi) << 16);
            }
        } else {
            const float* A = (const float*)Araw;
            float v[16];
#pragma unroll
            for (int t = 0; t < 16; ++t) v[t] = 0.f;
            if (gr < N_NODES) {
                const float* ap = A + (long)gr * K + k0 + ako;
#pragma unroll
                for (int t = 0; t < 4; ++t) {
                    float4 f = *(const float4*)(ap + t * 4);
                    v[t * 4 + 0] = f.x; v[t * 4 + 1] = f.y; v[t * 4 + 2] = f.z; v[t * 4 + 3] = f.w;
                }
            }
#pragma unroll
            for (int t = 0; t < 8; ++t) {
                int k = k0 + ako + t * 2;
                float lo = v[t * 2] * aff_a[k] + aff_b[k];
                float hi = v[t * 2 + 1] * aff_a[k + 1] + aff_b[k + 1];
                ow[t] = (uint_t)f2bf(lo) | ((uint_t)f2bf(hi) << 16);
            }
        }
        uint4 bv = *(const uint4*)(Bt + (long)(col0 + br) * K + k0 + bko);
        *(uint4*)&As[ar][ako] = make_uint4(ow[0], ow[1], ow[2], ow[3]);
        *(uint4*)&As[ar][ako + 8] = make_uint4(ow[4], ow[5], ow[6], ow[7]);
        *(uint4*)&Bs[br][bko] = bv;
        __syncthreads();

        bf16x8 af[2], bf[4];
#pragma unroll
        for (int r = 0; r < 2; ++r)
            af[r] = *(const bf16x8*)&As[w * 32 + r * 16 + m_l][q * 8];
#pragma unroll
        for (int c = 0; c < 4; ++c)
            bf[c] = *(const bf16x8*)&Bs[c * 16 + m_l][q * 8];
#pragma unroll
        for (int r = 0; r < 2; ++r)
#pragma unroll
            for (int c = 0; c < 4; ++c)
                acc[r][c] = __builtin_amdgcn_mfma_f32_16x16x32_bf16(af[r], bf[c], acc[r][c], 0, 0, 0);
        __syncthreads();
    }

#pragma unroll
    for (int r = 0; r < 2; ++r)
#pragma unroll
        for (int c = 0; c < 4; ++c)
#pragma unroll
            for (int i = 0; i < 4; ++i)
                Cs[w][r * 16 + q * 4 + i][c * 16 + m_l] = f2bf(acc[r][c][i]);
    const int H = NFULL / 64;
#pragma unroll
    for (int j = 0; j < 4; ++j) {
        int flat = j * 64 + lane;
        int lr = flat >> 3, chg = flat & 7;
        int gr = row0 + w * 32 + lr;
        uint4 u = *(uint4*)&Cs[w][lr][chg * 8];
        float f0 = bflo(u.x), f1 = bfhi(u.x), f2 = bflo(u.y), f3 = bfhi(u.y);
        float f4 = bflo(u.z), f5 = bfhi(u.z), f6 = bflo(u.w), f7 = bfhi(u.w);
        int cb = chg * 8;
        float s1 = f0 * asrc_s[cb] + f1 * asrc_s[cb + 1] + f2 * asrc_s[cb + 2] + f3 * asrc_s[cb + 3]
                 + f4 * asrc_s[cb + 4] + f5 * asrc_s[cb + 5] + f6 * asrc_s[cb + 6] + f7 * asrc_s[cb + 7];
        float s2 = f0 * adst_s[cb] + f1 * adst_s[cb + 1] + f2 * adst_s[cb + 2] + f3 * adst_s[cb + 3]
                 + f4 * adst_s[cb + 4] + f5 * adst_s[cb + 5] + f6 * adst_s[cb + 6] + f7 * adst_s[cb + 7];
#pragma unroll
        for (int o = 1; o < 8; o <<= 1) {
            s1 += __shfl_xor(s1, o, 64);
            s2 += __shfl_xor(s2, o, 64);
        }
        if (gr < N_NODES) {
            *(uint4*)(C + (long)gr * NFULL + col0 + chg * 8) = u;
            if ((lane & 7) == 0) {
                as_[gr * H + blockIdx.y] = s1;
                ad_[gr * H + blockIdx.y] = s2;
            }
        }
    }
}

// ---------------- GAT aggregation H=4: quarter-wave (16 lanes) per dst, 16 dst/block ----------------
// lane cl covers channels cl*16..cl*16+15 (2x uint4); bf16 output (pre-BN)
__global__ __launch_bounds__(256) void agg4_kernel(const ushort_t* __restrict__ h,
                                                   const float* __restrict__ as_,
                                                   const float* __restrict__ ad_,
                                                   const int* __restrict__ rowptr,
                                                   const int* __restrict__ srcs,
                                                   const float* __restrict__ bias,
                                                   ushort_t* __restrict__ out) {
    __shared__ float alds[4][256];   // [wave][dst_slot(64) * 4 heads]
    int lane = threadIdx.x & 63, w = threadIdx.x >> 6;
    int q = lane >> 4, cl = lane & 15;
    int n = blockIdx.x * 16 + w * 4 + q;
    if (n >= N_NODES) return;
    int start = rowptr[n];
    int deg = rowptr[n + 1] - start;

    float4 adv = *(const float4*)(ad_ + n * 4);
    float ad4[4] = {adv.x, adv.y, adv.z, adv.w};

    // pass 1: per-lane online softmax over edges cl, cl+16, ...; stage chunk-0 logits
    float mx[4] = {-1e30f, -1e30f, -1e30f, -1e30f};
    float dn[4] = {0.f, 0.f, 0.f, 0.f};
    int s0reg = 0;
    {
        float vst[4] = {-1e30f, -1e30f, -1e30f, -1e30f};
        if (deg > 0) s0reg = srcs[start + min(cl, deg - 1)];
        if (cl < deg) {
            float4 av = *(const float4*)(as_ + s0reg * 4);
            float vv[4] = {av.x + ad4[0], av.y + ad4[1], av.z + ad4[2], av.w + ad4[3]};
#pragma unroll
            for (int hh = 0; hh < 4; ++hh) {
                float v = vv[hh] > 0.f ? vv[hh] : 0.2f * vv[hh];
                vst[hh] = v; mx[hh] = v; dn[hh] = 1.f;
            }
        }
        *(float4*)&alds[w][lane * 4] = make_float4(vst[0], vst[1], vst[2], vst[3]);
        for (int j = cl + 16; j < deg; j += 16) {
            int s = srcs[start + j];
            float4 av = *(const float4*)(as_ + s * 4);
            float vv[4] = {av.x + ad4[0], av.y + ad4[1], av.z + ad4[2], av.w + ad4[3]};
#pragma unroll
            for (int hh = 0; hh < 4; ++hh) {
                float v = vv[hh] > 0.f ? vv[hh] : 0.2f * vv[hh];
                float mn = fmaxf(mx[hh], v);
                dn[hh] = dn[hh] * __expf(mx[hh] - mn) + __expf(v - mn);
                mx[hh] = mn;
            }
        }
    }
    // 4-step butterfly within quarter
    float mloc[4] = {mx[0], mx[1], mx[2], mx[3]};
#pragma unroll
    for (int off = 1; off < 16; off <<= 1)
#pragma unroll
        for (int hh = 0; hh < 4; ++hh) mx[hh] = fmaxf(mx[hh], __shfl_xor(mx[hh], off, 64));
#pragma unroll
    for (int hh = 0; hh < 4; ++hh) dn[hh] *= __expf(mloc[hh] - mx[hh]);
#pragma unroll
    for (int off = 1; off < 16; off <<= 1)
#pragma unroll
        for (int hh = 0; hh < 4; ++hh) dn[hh] += __shfl_xor(dn[hh], off, 64);
    float inv[4];
#pragma unroll
    for (int hh = 0; hh < 4; ++hh) inv[hh] = dn[hh] > 0.f ? 1.f / dn[hh] : 0.f;

    // chunk-0 logits -> alphas in place
    {
        float4 vv = *(const float4*)&alds[w][lane * 4];
        float4 al;
        al.x = __expf(vv.x - mx[0]) * inv[0];
        al.y = __expf(vv.y - mx[1]) * inv[1];
        al.z = __expf(vv.z - mx[2]) * inv[2];
        al.w = __expf(vv.w - mx[3]) * inv[3];
        *(float4*)&alds[w][lane * 4] = al;
    }

    int hd = cl >> 2;   // head of channel block cl*16
    float acc[16];
#pragma unroll
    for (int k = 0; k < 16; ++k) acc[k] = 0.f;
    for (int chunk = 0; chunk < deg || chunk == 0; chunk += 16) {
        int s = s0reg;
        if (chunk > 0) {
            int j = chunk + cl;
            float4 al = make_float4(0.f, 0.f, 0.f, 0.f);
            s = srcs[start + min(j, deg - 1)];
            if (j < deg) {
                float4 av = *(const float4*)(as_ + s * 4);
                float vv[4] = {av.x + ad4[0], av.y + ad4[1], av.z + ad4[2], av.w + ad4[3]};
                float a4[4];
#pragma unroll
                for (int hh = 0; hh < 4; ++hh) {
                    float v = vv[hh] > 0.f ? vv[hh] : 0.2f * vv[hh];
                    a4[hh] = __expf(v - mx[hh]) * inv[hh];
                }
                al = make_float4(a4[0], a4[1], a4[2], a4[3]);
            }
            *(float4*)&alds[w][lane * 4] = al;
        }
        int cnt = min(16, deg - chunk);
        if (cnt < 0) cnt = 0;
#pragma unroll 4
        for (int e = 0; e < cnt; ++e) {
            int se = __shfl(s, q * 16 + e, 64);
            float al = alds[w][(q * 16 + e) * 4 + hd];
            const ushort_t* hr = h + (long)se * 256 + cl * 16;
            uint4 u0 = *(const uint4*)hr;
            uint4 u1 = *(const uint4*)(hr + 8);
            acc[0] += al * bflo(u0.x);  acc[1] += al * bfhi(u0.x);
            acc[2] += al * bflo(u0.y);  acc[3] += al * bfhi(u0.y);
            acc[4] += al * bflo(u0.z);  acc[5] += al * bfhi(u0.z);
            acc[6] += al * bflo(u0.w);  acc[7] += al * bfhi(u0.w);
            acc[8] += al * bflo(u1.x);  acc[9] += al * bfhi(u1.x);
            acc[10] += al * bflo(u1.y); acc[11] += al * bfhi(u1.y);
            acc[12] += al * bflo(u1.z); acc[13] += al * bfhi(u1.z);
            acc[14] += al * bflo(u1.w); acc[15] += al * bfhi(u1.w);
        }
        if (deg <= 16) break;
    }
    // epilogue: +bias, relu, pack bf16, write 2x uint4
    int c0 = cl * 16;
    uint_t ow[8];
#pragma unroll
    for (int t = 0; t < 8; ++t) {
        float lo = fmaxf(acc[t * 2] + bias[c0 + t * 2], 0.f);
        float hi = fmaxf(acc[t * 2 + 1] + bias[c0 + t * 2 + 1], 0.f);
        ow[t] = (uint_t)f2bf(lo) | ((uint_t)f2bf(hi) << 16);
    }
    ushort_t* op = out + (long)n * 256 + c0;
    *(uint4*)op = make_uint4(ow[0], ow[1], ow[2], ow[3]);
    *(uint4*)(op + 8) = make_uint4(ow[4], ow[5], ow[6], ow[7]);
}

// ---------------- GAT aggregation H=1: octant (8 lanes) per dst, 32 dst/block ----------------
__global__ __launch_bounds__(256) void agg1_kernel(const ushort_t* __restrict__ h,
                                                   const float* __restrict__ as_,
                                                   const float* __restrict__ ad_,
                                                   const int* __restrict__ rowptr,
                                                   const int* __restrict__ srcs,
                                                   const float* __restrict__ bias,
                                                   ushort_t* __restrict__ out) {
    __shared__ float alds1[4][64];
    int lane = threadIdx.x & 63, w = threadIdx.x >> 6;
    int o = lane >> 3, cl = lane & 7;
    int n = blockIdx.x * 32 + w * 8 + o;
    if (n >= N_NODES) return;
    int start = rowptr[n];
    int deg = rowptr[n + 1] - start;
    float adn = ad_[n];

    float mx = -1e30f, dn = 0.f;
    int s0reg = 0;
    {
        float vst = -1e30f;
        if (deg > 0) s0reg = srcs[start + min(cl, deg - 1)];
        if (cl < deg) {
            float v = as_[s0reg] + adn;
            v = v > 0.f ? v : 0.2f * v;
            vst = v; mx = v; dn = 1.f;
        }
        alds1[w][lane] = vst;
        for (int j = cl + 8; j < deg; j += 8) {
            int s = srcs[start + j];
            float v = as_[s] + adn;
            v = v > 0.f ? v : 0.2f * v;
            float mn = fmaxf(mx, v);
            dn = dn * __expf(mx - mn) + __expf(v - mn);
            mx = mn;
        }
    }
    float mloc = mx;
#pragma unroll
    for (int off = 1; off < 8; off <<= 1) mx = fmaxf(mx, __shfl_xor(mx, off, 64));
    dn *= __expf(mloc - mx);
#pragma unroll
    for (int off = 1; off < 8; off <<= 1) dn += __shfl_xor(dn, off, 64);
    float inv = dn > 0.f ? 1.f / dn : 0.f;

    alds1[w][lane] = __expf(alds1[w][lane] - mx) * inv;

    float acc[8] = {0.f, 0.f, 0.f, 0.f, 0.f, 0.f, 0.f, 0.f};
    for (int chunk = 0; chunk < deg || chunk == 0; chunk += 8) {
        int s = s0reg;
        if (chunk > 0) {
            int j = chunk + cl;
            float al = 0.f;
            s = srcs[start + min(j, deg - 1)];
            if (j < deg) {
                float v = as_[s] + adn;
                v = v > 0.f ? v : 0.2f * v;
                al = __expf(v - mx) * inv;
            }
            alds1[w][lane] = al;
        }
        int cnt = min(8, deg - chunk);
        if (cnt < 0) cnt = 0;
#pragma unroll 4
        for (int e = 0; e < cnt; ++e) {
            int se = __shfl(s, o * 8 + e, 64);
            float al = alds1[w][o * 8 + e];
            const ushort_t* hr = h + (long)se * 64 + cl * 8;
            uint4 u = *(const uint4*)hr;
            acc[0] += al * bflo(u.x); acc[1] += al * bfhi(u.x);
            acc[2] += al * bflo(u.y); acc[3] += al * bfhi(u.y);
            acc[4] += al * bflo(u.z); acc[5] += al * bfhi(u.z);
            acc[6] += al * bflo(u.w); acc[7] += al * bfhi(u.w);
        }
        if (deg <= 8) break;
    }
    int c0 = cl * 8;
    uint_t ow[4];
#pragma unroll
    for (int t = 0; t < 4; ++t) {
        float lo = fmaxf(acc[t * 2] + bias[c0 + t * 2], 0.f);
        float hi = fmaxf(acc[t * 2 + 1] + bias[c0 + t * 2 + 1], 0.f);
        ow[t] = (uint_t)f2bf(lo) | ((uint_t)f2bf(hi) << 16);
    }
    *(uint4*)(out + (long)n * 64 + c0) = make_uint4(ow[0], ow[1], ow[2], ow[3]);
}

// ---------------- BatchNorm stats on bf16, coalesced ----------------
template<int C>
__global__ __launch_bounds__(256) void bn_stats_bf16(const ushort_t* __restrict__ x,
                                                     float* __restrict__ stats) {
    const int GROUPS = C / 8;        // ch-groups of 8
    const int RS = 256 / GROUPS;     // row slots per block
    int tid = threadIdx.x;
    int cg = tid % GROUPS;
    int rs = tid / GROUPS;
    float s[8], s2[8];
#pragma unroll
    for (int k = 0; k < 8; ++k) { s[k] = 0.f; s2[k] = 0.f; }
    for (int n = blockIdx.x * RS + rs; n < N_NODES; n += gridDim.x * RS) {
        uint4 u = *(const uint4*)(x + (long)n * C + cg * 8);
        float f[8] = {bflo(u.x), bfhi(u.x), bflo(u.y), bfhi(u.y),
                      bflo(u.z), bfhi(u.z), bflo(u.w), bfhi(u.w)};
#pragma unroll
        for (int k = 0; k < 8; ++k) { s[k] += f[k]; s2[k] += f[k] * f[k]; }
    }
    __shared__ float red[256][16];
#pragma unroll
    for (int k = 0; k < 8; ++k) { red[tid][k] = s[k]; red[tid][8 + k] = s2[k]; }
    __syncthreads();
    if (tid < C) {
        int g = tid >> 3, k = tid & 7;
        float a = 0.f, b = 0.f;
        for (int r = 0; r < RS; ++r) {
            a += red[g + r * GROUPS][k];
            b += red[g + r * GROUPS][8 + k];
        }
        atomicAdd(&stats[tid], a);
        atomicAdd(&stats[256 + tid], b);
    }
}

// ---------------- pool (BN affine fused) + FC ----------------
__global__ void batch_offsets_kernel(const int* __restrict__ batch, int* __restrict__ goff) {
    int g = threadIdx.x;
    if (g > NUM_GRAPHS) return;
    int lo = 0, hi = N_NODES;
    while (lo < hi) {
        int mid = (lo + hi) >> 1;
        if (batch[mid] < g) lo = mid + 1; else hi = mid;
    }
    goff[g] = lo;
}

__global__ __launch_bounds__(256) void pool2_kernel(const ushort_t* __restrict__ h,
                                                    const int* __restrict__ goff,
                                                    const float* __restrict__ stats,
                                                    const float* __restrict__ g3,
                                                    const float* __restrict__ be3,
                                                    float* __restrict__ pooled) {
    int g = blockIdx.x;
    int c = threadIdx.x & 63;
    int ty = threadIdx.x >> 6;
    int s = goff[g], e = goff[g + 1];
    float sum = 0.f;
    for (int n = s + ty; n < e; n += 4) sum += bflo((uint_t)h[(long)n * 64 + c]);
    __shared__ float red[4][64];
    red[ty][c] = sum;
    __syncthreads();
    if (ty == 0) {
        float tot = red[0][c] + red[1][c] + red[2][c] + red[3][c];
        float v = tot / fmaxf((float)(e - s), 1.f);
        float m = stats[c] * (1.f / N_NODES);
        float var = fmaxf(stats[256 + c] * (1.f / N_NODES) - m * m, 0.f);
        pooled[g * 64 + c] = (v - m) * rsqrtf(var + EPS_BN) * g3[c] + be3[c];
    }
}

__global__ void fc_kernel(const float* __restrict__ pooled, const float* __restrict__ fcW,
                          const float* __restrict__ fcb, float* __restrict__ out) {
    int i = blockIdx.x * blockDim.x + threadIdx.x;
    if (i >= NUM_GRAPHS * 10) return;
    int g = i / 10, j = i % 10;
    float s = 0.f;
    for (int k = 0; k < 64; ++k) s += pooled[g * 64 + k] * fcW[k * 10 + j];
    out[i] = s + fcb[j];
}

extern "C" void kernel_launch(void* const* d_in, const int* in_sizes, int n_in,
                              void* d_out, int out_size, void* d_ws, size_t ws_size,
                              hipStream_t stream) {
    const float* x      = (const float*)d_in[0];
    const int*   ei     = (const int*)d_in[1];
    const int*   batch  = (const int*)d_in[2];
    const float* W1     = (const float*)d_in[3];
    const float* a_src1 = (const float*)d_in[4];
    const float* a_dst1 = (const float*)d_in[5];
    const float* b1     = (const float*)d_in[6];
    const float* g1     = (const float*)d_in[7];
    const float* be1    = (const float*)d_in[8];
    const float* W2     = (const float*)d_in[9];
    const float* a_src2 = (const float*)d_in[10];
    const float* a_dst2 = (const float*)d_in[11];
    const float* b2     = (const float*)d_in[12];
    const float* g2     = (const float*)d_in[13];
    const float* be2    = (const float*)d_in[14];
    const float* W3     = (const float*)d_in[15];
    const float* a_src3 = (const float*)d_in[16];
    const float* a_dst3 = (const float*)d_in[17];
    const float* b3     = (const float*)d_in[18];
    const float* g3     = (const float*)d_in[19];
    const float* be3    = (const float*)d_in[20];
    const float* fcW    = (const float*)d_in[21];
    const float* fcb    = (const float*)d_in[22];
    float* out = (float*)d_out;

    const size_t N = N_NODES, E = NUM_E;
    ushort_t* hbf    = (ushort_t*)d_ws;                 // [N,256] bf16 GEMM output
    ushort_t* hagg   = hbf + N * 256;                   // [N,256] bf16 agg output (pre-BN)
    ushort_t* w1t    = hagg + N * 256;                  // [256][128]
    ushort_t* w2t    = w1t + 256 * 128;                 // [256][256]
    ushort_t* w3t    = w2t + 256 * 256;                 // [64][256]
    float*    as_    = (float*)(w3t + 64 * 256 + 128);  // [N,4]
    float*    ad_    = as_ + N * 4;                     // [N,4]
    int*      deg    = (int*)(ad_ + N * 4);             // [N]   (zero region start)
    int*      fill   = deg + N;                         // [N]
    float*    statsA = (float*)(fill + N);              // [512]
    float*    statsB = statsA + 512;                    // [512]
    float*    statsC = statsB + 512;                    // [512]
    int*      rowptr = (int*)(statsC + 512);            // [N+1]
    int*      srcs   = rowptr + (N + 1);                // [E]
    int*      bsum   = srcs + E;                        // [256]
    float*    pooled = (float*)(bsum + 256);            // [64*64]
    int*      goff   = (int*)(pooled + 64 * 64);        // [65]

    const int NB = (N_NODES + 255) / 256;  // 196

    hipMemsetAsync(deg, 0, sizeof(int) * (2 * N + 3 * 512), stream);
    hist_kernel<<<(NUM_E + 255) / 256, 256, 0, stream>>>(ei, deg);
    scan_local_kernel<<<NB, 256, 0, stream>>>(deg, rowptr, bsum);
    scan_sums_kernel<<<1, 256, 0, stream>>>(bsum, NB);
    scan_add_kernel<<<NB, 256, 0, stream>>>(rowptr, bsum);
    scatter_kernel<<<(NUM_E + 255) / 256, 256, 0, stream>>>(ei, rowptr, fill, srcs);
    batch_offsets_kernel<<<1, 128, 0, stream>>>(batch, goff);
    prep_w_all<<<(128 * 256 + 256 * 256 + 256 * 64 + 255) / 256, 256, 0, stream>>>(W1, W2, W3, w1t, w2t, w3t);

    const int GB = (N_NODES + 127) / 128;  // 391

    // ---- layer 1: A = x fp32 (identity affine) ----
    gemm_fused_kernel<128, 256, false><<<dim3(GB, 4), 256, 0, stream>>>(
        x, w1t, hbf, nullptr, nullptr, nullptr, a_src1, a_dst1, as_, ad_);
    agg4_kernel<<<(N_NODES + 15) / 16, 256, 0, stream>>>(hbf, as_, ad_, rowptr, srcs, b1, hagg);
    bn_stats_bf16<256><<<128, 256, 0, stream>>>(hagg, statsA);

    // ---- layer 2: A = hagg bf16 + BN(statsA) affine ----
    gemm_fused_kernel<256, 256, true><<<dim3(GB, 4), 256, 0, stream>>>(
        hagg, w2t, hbf, statsA, g1, be1, a_src2, a_dst2, as_, ad_);
    agg4_kernel<<<(N_NODES + 15) / 16, 256, 0, stream>>>(hbf, as_, ad_, rowptr, srcs, b2, hagg);
    bn_stats_bf16<256><<<128, 256, 0, stream>>>(hagg, statsB);

    // ---- layer 3: A = hagg bf16 + BN(statsB) affine ----
    gemm_fused_kernel<256, 64, true><<<dim3(GB, 1), 256, 0, stream>>>(
        hagg, w3t, hbf, statsB, g2, be2, a_src3, a_dst3, as_, ad_);
    agg1_kernel<<<(N_NODES + 31) / 32, 256, 0, stream>>>(hbf, as_, ad_, rowptr, srcs, b3, hagg);
    bn_stats_bf16<64><<<128, 256, 0, stream>>>(hagg, statsC);

    // ---- pool (BN3 affine fused) + FC ----
    pool2_kernel<<<NUM_GRAPHS, 256, 0, stream>>>(hagg, goff, statsC, g3, be3, pooled);
    fc_kernel<<<3, 256, 0, stream>>>(pooled, fcW, fcb, out);
}

// Round 8
// 513.951 us; speedup vs baseline: 2.8208x; 1.0095x over previous
//
#include <hip/hip_runtime.h>
#include <hip/hip_bf16.h>

#define N_NODES 50000
#define NUM_E   800000
#define EPS_BN  1e-5f
#define NUM_GRAPHS 64

typedef __attribute__((ext_vector_type(8))) short bf16x8;
typedef __attribute__((ext_vector_type(4))) float f32x4;
typedef unsigned short ushort_t;
typedef unsigned int uint_t;

static __device__ __forceinline__ unsigned short f2bf(float f) {
    unsigned int u = __float_as_uint(f);
    u += 0x7fffu + ((u >> 16) & 1u);   // RNE
    return (unsigned short)(u >> 16);
}
// packed f32x2 -> bf16x2 (v_cvt_pk_bf16_f32 on gfx950), lo in low 16 bits
static __device__ __forceinline__ uint_t pkbf(float lo, float hi) {
    __hip_bfloat162 t = __float22bfloat162_rn(make_float2(lo, hi));
    return *(uint_t*)&t;
}
static __device__ __forceinline__ float bflo(uint_t u) { return __uint_as_float(u << 16); }
static __device__ __forceinline__ float bfhi(uint_t u) { return __uint_as_float(u & 0xffff0000u); }

// ---------------- CSR build ----------------
__global__ void hist_kernel(const int* __restrict__ ei, int* __restrict__ deg) {
    int e = blockIdx.x * blockDim.x + threadIdx.x;
    if (e >= NUM_E) return;
    atomicAdd(&deg[ei[NUM_E + e]], 1);
}

__global__ void scan_local_kernel(const int* __restrict__ deg, int* __restrict__ rowptr,
                                  int* __restrict__ bsum) {
    __shared__ int ws[4];
    int b = blockIdx.x, t = threadIdx.x;
    int i = b * 256 + t;
    int lane = t & 63, wv = t >> 6;
    int v = (i < N_NODES) ? deg[i] : 0;
    int incl = v;
#pragma unroll
    for (int off = 1; off < 64; off <<= 1) {
        int u = __shfl_up(incl, off, 64);
        if (lane >= off) incl += u;
    }
    if (lane == 63) ws[wv] = incl;
    __syncthreads();
    if (t == 0) {
        int s = 0;
#pragma unroll
        for (int k = 0; k < 4; ++k) { int x = ws[k]; ws[k] = s; s += x; }
        bsum[b] = s;
    }
    __syncthreads();
    if (i < N_NODES) rowptr[i + 1] = ws[wv] + incl;
}

__global__ void scan_sums_kernel(int* __restrict__ bsum, int nb) {
    __shared__ int ws[4];
    int t = threadIdx.x;
    int lane = t & 63, wv = t >> 6;
    int v = (t < nb) ? bsum[t] : 0;
    int incl = v;
#pragma unroll
    for (int off = 1; off < 64; off <<= 1) {
        int u = __shfl_up(incl, off, 64);
        if (lane >= off) incl += u;
    }
    if (lane == 63) ws[wv] = incl;
    __syncthreads();
    if (t == 0) {
        int s = 0;
#pragma unroll
        for (int k = 0; k < 4; ++k) { int x = ws[k]; ws[k] = s; s += x; }
    }
    __syncthreads();
    if (t < nb) bsum[t] = ws[wv] + incl - v;   // exclusive
}

__global__ void scan_add_kernel(int* __restrict__ rowptr, const int* __restrict__ bsum) {
    int b = blockIdx.x, t = threadIdx.x;
    int i = b * 256 + t;
    if (i < N_NODES) rowptr[i + 1] += bsum[b];
    if (b == 0 && t == 0) rowptr[0] = 0;
}

__global__ void scatter_kernel(const int* __restrict__ ei, const int* __restrict__ rowptr,
                               int* __restrict__ fill, int* __restrict__ srcs) {
    int e = blockIdx.x * blockDim.x + threadIdx.x;
    if (e >= NUM_E) return;
    int dst = ei[NUM_E + e];
    int pos = rowptr[dst] + atomicAdd(&fill[dst], 1);
    srcs[pos] = ei[e];
}

// ---------------- weight prep ----------------
__global__ void prep_w_all(const float* __restrict__ W1, const float* __restrict__ W2,
                           const float* __restrict__ W3, ushort_t* __restrict__ w1t,
                           ushort_t* __restrict__ w2t, ushort_t* __restrict__ w3t) {
    int i = blockIdx.x * blockDim.x + threadIdx.x;
    const int S1 = 128 * 256, S2 = 256 * 256, S3 = 256 * 64;
    if (i < S1) {
        int k = i / 256, n = i % 256;
        w1t[n * 128 + k] = f2bf(W1[i]);
    } else if (i < S1 + S2) {
        int j = i - S1; int k = j / 256, n = j % 256;
        w2t[n * 256 + k] = f2bf(W2[j]);
    } else if (i < S1 + S2 + S3) {
        int j = i - S1 - S2; int k = j / 64, n = j % 64;
        w3t[n * 256 + k] = f2bf(W3[j]);
    }
}

// ---------------- fused GEMM: BN-affine(A)->bf16 @ Bt^T -> h(bf16) + per-head logits ----------------
// BM=128 rows, BN cols per block (BN=128: 2 heads/block; BN=64: 1 head)
template<int K, int NFULL, int BN, bool ABF16>
__global__ __launch_bounds__(256) void gemm_fused_kernel(const void* __restrict__ Araw,
                                                         const ushort_t* __restrict__ Bt,
                                                         ushort_t* __restrict__ C,
                                                         const float* __restrict__ stats,
                                                         const float* __restrict__ g,
                                                         const float* __restrict__ be,
                                                         const float* __restrict__ a_src,
                                                         const float* __restrict__ a_dst,
                                                         float* __restrict__ as_,
                                                         float* __restrict__ ad_) {
    const int NT = BN / 16;       // n-tiles per wave
    const int NG = BN / 64;       // 64-col groups (heads) per block
    __shared__ __align__(16) ushort_t As[128][40];
    __shared__ __align__(16) ushort_t Bs[BN][40];
    __shared__ __align__(16) ushort_t Cs[4][32][64];
    __shared__ __align__(16) float aff_a[K], aff_b[K];
    __shared__ float asrc_s[BN], adst_s[BN];
    int tid = threadIdx.x;
    int lane = tid & 63, w = tid >> 6;
    int row0 = blockIdx.x * 128, col0 = blockIdx.y * BN;
    int m_l = lane & 15, q = lane >> 4;

    for (int c = tid; c < K; c += 256) {
        float a = 1.f, b = 0.f;
        if (stats) {
            float m = stats[c] * (1.f / N_NODES);
            float var = fmaxf(stats[256 + c] * (1.f / N_NODES) - m * m, 0.f);
            float rs = rsqrtf(var + EPS_BN) * g[c];
            a = rs; b = be[c] - m * rs;
        }
        aff_a[c] = a; aff_b[c] = b;
    }
    if (tid < BN) {
        asrc_s[tid] = a_src[col0 + tid];
        adst_s[tid] = a_dst[col0 + tid];
    }
    __syncthreads();

    f32x4 acc[2][NT];
#pragma unroll
    for (int r = 0; r < 2; ++r)
#pragma unroll
        for (int c = 0; c < NT; ++c) acc[r][c] = (f32x4){0.f, 0.f, 0.f, 0.f};

    int ar = tid >> 1, ako = (tid & 1) * 16;

    for (int k0 = 0; k0 < K; k0 += 32) {
        uint_t ow[8];
        int gr = row0 + ar;
        if constexpr (ABF16) {
            const ushort_t* A = (const ushort_t*)Araw;
            uint4 u0 = make_uint4(0, 0, 0, 0), u1 = make_uint4(0, 0, 0, 0);
            if (gr < N_NODES) {
                const ushort_t* ap = A + (long)gr * K + k0 + ako;
                u0 = *(const uint4*)ap;
                u1 = *(const uint4*)(ap + 8);
            }
            uint_t uu[8] = {u0.x, u0.y, u0.z, u0.w, u1.x, u1.y, u1.z, u1.w};
#pragma unroll
            for (int t = 0; t < 8; ++t) {
                int k = k0 + ako + t * 2;
                float lo = bflo(uu[t]) * aff_a[k] + aff_b[k];
                float hi = bfhi(uu[t]) * aff_a[k + 1] + aff_b[k + 1];
                ow[t] = pkbf(lo, hi);
            }
        } else {
            const float* A = (const float*)Araw;
            float v[16];
#pragma unroll
            for (int t = 0; t < 16; ++t) v[t] = 0.f;
            if (gr < N_NODES) {
                const float* ap = A + (long)gr * K + k0 + ako;
#pragma unroll
                for (int t = 0; t < 4; ++t) {
                    float4 f = *(const float4*)(ap + t * 4);
                    v[t * 4 + 0] = f.x; v[t * 4 + 1] = f.y; v[t * 4 + 2] = f.z; v[t * 4 + 3] = f.w;
                }
            }
#pragma unroll
            for (int t = 0; t < 8; ++t) {
                int k = k0 + ako + t * 2;
                float lo = v[t * 2] * aff_a[k] + aff_b[k];
                float hi = v[t * 2 + 1] * aff_a[k + 1] + aff_b[k + 1];
                ow[t] = pkbf(lo, hi);
            }
        }
        // B staging
        if constexpr (BN == 128) {
            int br = tid >> 1, bko = (tid & 1) * 16;
            const ushort_t* bp = Bt + (long)(col0 + br) * K + k0 + bko;
            uint4 b0 = *(const uint4*)bp;
            uint4 b1 = *(const uint4*)(bp + 8);
            *(uint4*)&As[ar][ako] = make_uint4(ow[0], ow[1], ow[2], ow[3]);
            *(uint4*)&As[ar][ako + 8] = make_uint4(ow[4], ow[5], ow[6], ow[7]);
            *(uint4*)&Bs[br][bko] = b0;
            *(uint4*)&Bs[br][bko + 8] = b1;
        } else {
            int br = tid >> 2, bko = (tid & 3) * 8;
            uint4 bv = *(const uint4*)(Bt + (long)(col0 + br) * K + k0 + bko);
            *(uint4*)&As[ar][ako] = make_uint4(ow[0], ow[1], ow[2], ow[3]);
            *(uint4*)&As[ar][ako + 8] = make_uint4(ow[4], ow[5], ow[6], ow[7]);
            *(uint4*)&Bs[br][bko] = bv;
        }
        __syncthreads();

        bf16x8 af[2];
#pragma unroll
        for (int r = 0; r < 2; ++r)
            af[r] = *(const bf16x8*)&As[w * 32 + r * 16 + m_l][q * 8];
#pragma unroll
        for (int c = 0; c < NT; ++c) {
            bf16x8 bf = *(const bf16x8*)&Bs[c * 16 + m_l][q * 8];
#pragma unroll
            for (int r = 0; r < 2; ++r)
                acc[r][c] = __builtin_amdgcn_mfma_f32_16x16x32_bf16(af[r], bf, acc[r][c], 0, 0, 0);
        }
        __syncthreads();
    }

    const int H = NFULL / 64;
#pragma unroll
    for (int gblk = 0; gblk < NG; ++gblk) {
        int hidx = blockIdx.y * NG + gblk;
        int colg = col0 + gblk * 64;
#pragma unroll
        for (int r = 0; r < 2; ++r)
#pragma unroll
            for (int cc = 0; cc < 4; ++cc)
#pragma unroll
                for (int i = 0; i < 4; ++i)
                    Cs[w][r * 16 + q * 4 + i][cc * 16 + m_l] = f2bf(acc[r][gblk * 4 + cc][i]);
        // same-wave LDS RAW: in-order DS pipe, no barrier needed
#pragma unroll
        for (int j = 0; j < 4; ++j) {
            int flat = j * 64 + lane;
            int lr = flat >> 3, chg = flat & 7;
            int gr = row0 + w * 32 + lr;
            uint4 u = *(uint4*)&Cs[w][lr][chg * 8];
            float f0 = bflo(u.x), f1 = bfhi(u.x), f2 = bflo(u.y), f3 = bfhi(u.y);
            float f4 = bflo(u.z), f5 = bfhi(u.z), f6 = bflo(u.w), f7 = bfhi(u.w);
            int cb = gblk * 64 + chg * 8;
            float s1 = f0 * asrc_s[cb] + f1 * asrc_s[cb + 1] + f2 * asrc_s[cb + 2] + f3 * asrc_s[cb + 3]
                     + f4 * asrc_s[cb + 4] + f5 * asrc_s[cb + 5] + f6 * asrc_s[cb + 6] + f7 * asrc_s[cb + 7];
            float s2 = f0 * adst_s[cb] + f1 * adst_s[cb + 1] + f2 * adst_s[cb + 2] + f3 * adst_s[cb + 3]
                     + f4 * adst_s[cb + 4] + f5 * adst_s[cb + 5] + f6 * adst_s[cb + 6] + f7 * adst_s[cb + 7];
#pragma unroll
            for (int o = 1; o < 8; o <<= 1) {
                s1 += __shfl_xor(s1, o, 64);
                s2 += __shfl_xor(s2, o, 64);
            }
            if (gr < N_NODES) {
                *(uint4*)(C + (long)gr * NFULL + colg + chg * 8) = u;
                if ((lane & 7) == 0) {
                    as_[gr * H + hidx] = s1;
                    ad_[gr * H + hidx] = s2;
                }
            }
        }
    }
}

// ---------------- GAT aggregation H=4: quarter-wave (16 lanes) per dst, 16 dst/block ----------------
__global__ __launch_bounds__(256) void agg4_kernel(const ushort_t* __restrict__ h,
                                                   const float* __restrict__ as_,
                                                   const float* __restrict__ ad_,
                                                   const int* __restrict__ rowptr,
                                                   const int* __restrict__ srcs,
                                                   const float* __restrict__ bias,
                                                   ushort_t* __restrict__ out) {
    __shared__ float alds[4][256];
    int lane = threadIdx.x & 63, w = threadIdx.x >> 6;
    int q = lane >> 4, cl = lane & 15;
    int n = blockIdx.x * 16 + w * 4 + q;
    if (n >= N_NODES) return;
    int start = rowptr[n];
    int deg = rowptr[n + 1] - start;

    float4 adv = *(const float4*)(ad_ + n * 4);
    float ad4[4] = {adv.x, adv.y, adv.z, adv.w};

    float mx[4] = {-1e30f, -1e30f, -1e30f, -1e30f};
    float dn[4] = {0.f, 0.f, 0.f, 0.f};
    int s0reg = 0;
    {
        float vst[4] = {-1e30f, -1e30f, -1e30f, -1e30f};
        if (deg > 0) s0reg = srcs[start + min(cl, deg - 1)];
        if (cl < deg) {
            float4 av = *(const float4*)(as_ + s0reg * 4);
            float vv[4] = {av.x + ad4[0], av.y + ad4[1], av.z + ad4[2], av.w + ad4[3]};
#pragma unroll
            for (int hh = 0; hh < 4; ++hh) {
                float v = vv[hh] > 0.f ? vv[hh] : 0.2f * vv[hh];
                vst[hh] = v; mx[hh] = v; dn[hh] = 1.f;
            }
        }
        *(float4*)&alds[w][lane * 4] = make_float4(vst[0], vst[1], vst[2], vst[3]);
        for (int j = cl + 16; j < deg; j += 16) {
            int s = srcs[start + j];
            float4 av = *(const float4*)(as_ + s * 4);
            float vv[4] = {av.x + ad4[0], av.y + ad4[1], av.z + ad4[2], av.w + ad4[3]};
#pragma unroll
            for (int hh = 0; hh < 4; ++hh) {
                float v = vv[hh] > 0.f ? vv[hh] : 0.2f * vv[hh];
                float mn = fmaxf(mx[hh], v);
                dn[hh] = dn[hh] * __expf(mx[hh] - mn) + __expf(v - mn);
                mx[hh] = mn;
            }
        }
    }
    float mloc[4] = {mx[0], mx[1], mx[2], mx[3]};
#pragma unroll
    for (int off = 1; off < 16; off <<= 1)
#pragma unroll
        for (int hh = 0; hh < 4; ++hh) mx[hh] = fmaxf(mx[hh], __shfl_xor(mx[hh], off, 64));
#pragma unroll
    for (int hh = 0; hh < 4; ++hh) dn[hh] *= __expf(mloc[hh] - mx[hh]);
#pragma unroll
    for (int off = 1; off < 16; off <<= 1)
#pragma unroll
        for (int hh = 0; hh < 4; ++hh) dn[hh] += __shfl_xor(dn[hh], off, 64);
    float inv[4];
#pragma unroll
    for (int hh = 0; hh < 4; ++hh) inv[hh] = dn[hh] > 0.f ? 1.f / dn[hh] : 0.f;

    {
        float4 vv = *(const float4*)&alds[w][lane * 4];
        float4 al;
        al.x = __expf(vv.x - mx[0]) * inv[0];
        al.y = __expf(vv.y - mx[1]) * inv[1];
        al.z = __expf(vv.z - mx[2]) * inv[2];
        al.w = __expf(vv.w - mx[3]) * inv[3];
        *(float4*)&alds[w][lane * 4] = al;
    }

    int hd = cl >> 2;
    float acc[16];
#pragma unroll
    for (int k = 0; k < 16; ++k) acc[k] = 0.f;
    for (int chunk = 0; chunk < deg || chunk == 0; chunk += 16) {
        int s = s0reg;
        if (chunk > 0) {
            int j = chunk + cl;
            float4 al = make_float4(0.f, 0.f, 0.f, 0.f);
            s = srcs[start + min(j, deg - 1)];
            if (j < deg) {
                float4 av = *(const float4*)(as_ + s * 4);
                float vv[4] = {av.x + ad4[0], av.y + ad4[1], av.z + ad4[2], av.w + ad4[3]};
                float a4[4];
#pragma unroll
                for (int hh = 0; hh < 4; ++hh) {
                    float v = vv[hh] > 0.f ? vv[hh] : 0.2f * vv[hh];
                    a4[hh] = __expf(v - mx[hh]) * inv[hh];
                }
                al = make_float4(a4[0], a4[1], a4[2], a4[3]);
            }
            *(float4*)&alds[w][lane * 4] = al;
        }
        int cnt = min(16, deg - chunk);
        if (cnt < 0) cnt = 0;
#pragma unroll 4
        for (int e = 0; e < cnt; ++e) {
            int se = __shfl(s, q * 16 + e, 64);
            float al = alds[w][(q * 16 + e) * 4 + hd];
            const ushort_t* hr = h + (long)se * 256 + cl * 16;
            uint4 u0 = *(const uint4*)hr;
            uint4 u1 = *(const uint4*)(hr + 8);
            acc[0] += al * bflo(u0.x);  acc[1] += al * bfhi(u0.x);
            acc[2] += al * bflo(u0.y);  acc[3] += al * bfhi(u0.y);
            acc[4] += al * bflo(u0.z);  acc[5] += al * bfhi(u0.z);
            acc[6] += al * bflo(u0.w);  acc[7] += al * bfhi(u0.w);
            acc[8] += al * bflo(u1.x);  acc[9] += al * bfhi(u1.x);
            acc[10] += al * bflo(u1.y); acc[11] += al * bfhi(u1.y);
            acc[12] += al * bflo(u1.z); acc[13] += al * bfhi(u1.z);
            acc[14] += al * bflo(u1.w); acc[15] += al * bfhi(u1.w);
        }
        if (deg <= 16) break;
    }
    int c0 = cl * 16;
    uint_t ow[8];
#pragma unroll
    for (int t = 0; t < 8; ++t) {
        float lo = fmaxf(acc[t * 2] + bias[c0 + t * 2], 0.f);
        float hi = fmaxf(acc[t * 2 + 1] + bias[c0 + t * 2 + 1], 0.f);
        ow[t] = pkbf(lo, hi);
    }
    ushort_t* op = out + (long)n * 256 + c0;
    *(uint4*)op = make_uint4(ow[0], ow[1], ow[2], ow[3]);
    *(uint4*)(op + 8) = make_uint4(ow[4], ow[5], ow[6], ow[7]);
}

// ---------------- GAT aggregation H=1: octant (8 lanes) per dst, 32 dst/block ----------------
__global__ __launch_bounds__(256) void agg1_kernel(const ushort_t* __restrict__ h,
                                                   const float* __restrict__ as_,
                                                   const float* __restrict__ ad_,
                                                   const int* __restrict__ rowptr,
                                                   const int* __restrict__ srcs,
                                                   const float* __restrict__ bias,
                                                   ushort_t* __restrict__ out) {
    __shared__ float alds1[4][64];
    int lane = threadIdx.x & 63, w = threadIdx.x >> 6;
    int o = lane >> 3, cl = lane & 7;
    int n = blockIdx.x * 32 + w * 8 + o;
    if (n >= N_NODES) return;
    int start = rowptr[n];
    int deg = rowptr[n + 1] - start;
    float adn = ad_[n];

    float mx = -1e30f, dn = 0.f;
    int s0reg = 0;
    {
        float vst = -1e30f;
        if (deg > 0) s0reg = srcs[start + min(cl, deg - 1)];
        if (cl < deg) {
            float v = as_[s0reg] + adn;
            v = v > 0.f ? v : 0.2f * v;
            vst = v; mx = v; dn = 1.f;
        }
        alds1[w][lane] = vst;
        for (int j = cl + 8; j < deg; j += 8) {
            int s = srcs[start + j];
            float v = as_[s] + adn;
            v = v > 0.f ? v : 0.2f * v;
            float mn = fmaxf(mx, v);
            dn = dn * __expf(mx - mn) + __expf(v - mn);
            mx = mn;
        }
    }
    float mloc = mx;
#pragma unroll
    for (int off = 1; off < 8; off <<= 1) mx = fmaxf(mx, __shfl_xor(mx, off, 64));
    dn *= __expf(mloc - mx);
#pragma unroll
    for (int off = 1; off < 8; off <<= 1) dn += __shfl_xor(dn, off, 64);
    float inv = dn > 0.f ? 1.f / dn : 0.f;

    alds1[w][lane] = __expf(alds1[w][lane] - mx) * inv;

    float acc[8] = {0.f, 0.f, 0.f, 0.f, 0.f, 0.f, 0.f, 0.f};
    for (int chunk = 0; chunk < deg || chunk == 0; chunk += 8) {
        int s = s0reg;
        if (chunk > 0) {
            int j = chunk + cl;
            float al = 0.f;
            s = srcs[start + min(j, deg - 1)];
            if (j < deg) {
                float v = as_[s] + adn;
                v = v > 0.f ? v : 0.2f * v;
                al = __expf(v - mx) * inv;
            }
            alds1[w][lane] = al;
        }
        int cnt = min(8, deg - chunk);
        if (cnt < 0) cnt = 0;
#pragma unroll 4
        for (int e = 0; e < cnt; ++e) {
            int se = __shfl(s, o * 8 + e, 64);
            float al = alds1[w][o * 8 + e];
            const ushort_t* hr = h + (long)se * 64 + cl * 8;
            uint4 u = *(const uint4*)hr;
            acc[0] += al * bflo(u.x); acc[1] += al * bfhi(u.x);
            acc[2] += al * bflo(u.y); acc[3] += al * bfhi(u.y);
            acc[4] += al * bflo(u.z); acc[5] += al * bfhi(u.z);
            acc[6] += al * bflo(u.w); acc[7] += al * bfhi(u.w);
        }
        if (deg <= 8) break;
    }
    int c0 = cl * 8;
    uint_t ow[4];
#pragma unroll
    for (int t = 0; t < 4; ++t) {
        float lo = fmaxf(acc[t * 2] + bias[c0 + t * 2], 0.f);
        float hi = fmaxf(acc[t * 2 + 1] + bias[c0 + t * 2 + 1], 0.f);
        ow[t] = pkbf(lo, hi);
    }
    *(uint4*)(out + (long)n * 64 + c0) = make_uint4(ow[0], ow[1], ow[2], ow[3]);
}

// ---------------- BatchNorm stats on bf16, coalesced ----------------
template<int C>
__global__ __launch_bounds__(256) void bn_stats_bf16(const ushort_t* __restrict__ x,
                                                     float* __restrict__ stats) {
    const int GROUPS = C / 8;
    const int RS = 256 / GROUPS;
    int tid = threadIdx.x;
    int cg = tid % GROUPS;
    int rs = tid / GROUPS;
    float s[8], s2[8];
#pragma unroll
    for (int k = 0; k < 8; ++k) { s[k] = 0.f; s2[k] = 0.f; }
    for (int n = blockIdx.x * RS + rs; n < N_NODES; n += gridDim.x * RS) {
        uint4 u = *(const uint4*)(x + (long)n * C + cg * 8);
        float f[8] = {bflo(u.x), bfhi(u.x), bflo(u.y), bfhi(u.y),
                      bflo(u.z), bfhi(u.z), bflo(u.w), bfhi(u.w)};
#pragma unroll
        for (int k = 0; k < 8; ++k) { s[k] += f[k]; s2[k] += f[k] * f[k]; }
    }
    __shared__ float red[256][16];
#pragma unroll
    for (int k = 0; k < 8; ++k) { red[tid][k] = s[k]; red[tid][8 + k] = s2[k]; }
    __syncthreads();
    if (tid < C) {
        int g = tid >> 3, k = tid & 7;
        float a = 0.f, b = 0.f;
        for (int r = 0; r < RS; ++r) {
            a += red[g + r * GROUPS][k];
            b += red[g + r * GROUPS][8 + k];
        }
        atomicAdd(&stats[tid], a);
        atomicAdd(&stats[256 + tid], b);
    }
}

// ---------------- pool (BN affine fused) + FC ----------------
__global__ void batch_offsets_kernel(const int* __restrict__ batch, int* __restrict__ goff) {
    int g = threadIdx.x;
    if (g > NUM_GRAPHS) return;
    int lo = 0, hi = N_NODES;
    while (lo < hi) {
        int mid = (lo + hi) >> 1;
        if (batch[mid] < g) lo = mid + 1; else hi = mid;
    }
    goff[g] = lo;
}

__global__ __launch_bounds__(256) void pool2_kernel(const ushort_t* __restrict__ h,
                                                    const int* __restrict__ goff,
                                                    const float* __restrict__ stats,
                                                    const float* __restrict__ g3,
                                                    const float* __restrict__ be3,
                                                    float* __restrict__ pooled) {
    int g = blockIdx.x;
    int c = threadIdx.x & 63;
    int ty = threadIdx.x >> 6;
    int s = goff[g], e = goff[g + 1];
    float sum = 0.f;
    for (int n = s + ty; n < e; n += 4) sum += bflo((uint_t)h[(long)n * 64 + c]);
    __shared__ float red[4][64];
    red[ty][c] = sum;
    __syncthreads();
    if (ty == 0) {
        float tot = red[0][c] + red[1][c] + red[2][c] + red[3][c];
        float v = tot / fmaxf((float)(e - s), 1.f);
        float m = stats[c] * (1.f / N_NODES);
        float var = fmaxf(stats[256 + c] * (1.f / N_NODES) - m * m, 0.f);
        pooled[g * 64 + c] = (v - m) * rsqrtf(var + EPS_BN) * g3[c] + be3[c];
    }
}

__global__ void fc_kernel(const float* __restrict__ pooled, const float* __restrict__ fcW,
                          const float* __restrict__ fcb, float* __restrict__ out) {
    int i = blockIdx.x * blockDim.x + threadIdx.x;
    if (i >= NUM_GRAPHS * 10) return;
    int g = i / 10, j = i % 10;
    float s = 0.f;
    for (int k = 0; k < 64; ++k) s += pooled[g * 64 + k] * fcW[k * 10 + j];
    out[i] = s + fcb[j];
}

extern "C" void kernel_launch(void* const* d_in, const int* in_sizes, int n_in,
                              void* d_out, int out_size, void* d_ws, size_t ws_size,
                              hipStream_t stream) {
    const float* x      = (const float*)d_in[0];
    const int*   ei     = (const int*)d_in[1];
    const int*   batch  = (const int*)d_in[2];
    const float* W1     = (const float*)d_in[3];
    const float* a_src1 = (const float*)d_in[4];
    const float* a_dst1 = (const float*)d_in[5];
    const float* b1     = (const float*)d_in[6];
    const float* g1     = (const float*)d_in[7];
    const float* be1    = (const float*)d_in[8];
    const float* W2     = (const float*)d_in[9];
    const float* a_src2 = (const float*)d_in[10];
    const float* a_dst2 = (const float*)d_in[11];
    const float* b2     = (const float*)d_in[12];
    const float* g2     = (const float*)d_in[13];
    const float* be2    = (const float*)d_in[14];
    const float* W3     = (const float*)d_in[15];
    const float* a_src3 = (const float*)d_in[16];
    const float* a_dst3 = (const float*)d_in[17];
    const float* b3     = (const float*)d_in[18];
    const float* g3     = (const float*)d_in[19];
    const float* be3    = (const float*)d_in[20];
    const float* fcW    = (const float*)d_in[21];
    const float* fcb    = (const float*)d_in[22];
    float* out = (float*)d_out;

    const size_t N = N_NODES, E = NUM_E;
    ushort_t* hbf    = (ushort_t*)d_ws;                 // [N,256] bf16 GEMM output
    ushort_t* hagg   = hbf + N * 256;                   // [N,256] bf16 agg output (pre-BN)
    ushort_t* w1t    = hagg + N * 256;                  // [256][128]
    ushort_t* w2t    = w1t + 256 * 128;                 // [256][256]
    ushort_t* w3t    = w2t + 256 * 256;                 // [64][256]
    float*    as_    = (float*)(w3t + 64 * 256 + 128);  // [N,4]
    float*    ad_    = as_ + N * 4;                     // [N,4]
    int*      deg    = (int*)(ad_ + N * 4);             // [N]   (zero region start)
    int*      fill   = deg + N;                         // [N]
    float*    statsA = (float*)(fill + N);              // [512]
    float*    statsB = statsA + 512;                    // [512]
    float*    statsC = statsB + 512;                    // [512]
    int*      rowptr = (int*)(statsC + 512);            // [N+1]
    int*      srcs   = rowptr + (N + 1);                // [E]
    int*      bsum   = srcs + E;                        // [256]
    float*    pooled = (float*)(bsum + 256);            // [64*64]
    int*      goff   = (int*)(pooled + 64 * 64);        // [65]

    const int NB = (N_NODES + 255) / 256;  // 196

    hipMemsetAsync(deg, 0, sizeof(int) * (2 * N + 3 * 512), stream);
    hist_kernel<<<(NUM_E + 255) / 256, 256, 0, stream>>>(ei, deg);
    scan_local_kernel<<<NB, 256, 0, stream>>>(deg, rowptr, bsum);
    scan_sums_kernel<<<1, 256, 0, stream>>>(bsum, NB);
    scan_add_kernel<<<NB, 256, 0, stream>>>(rowptr, bsum);
    scatter_kernel<<<(NUM_E + 255) / 256, 256, 0, stream>>>(ei, rowptr, fill, srcs);
    batch_offsets_kernel<<<1, 128, 0, stream>>>(batch, goff);
    prep_w_all<<<(128 * 256 + 256 * 256 + 256 * 64 + 255) / 256, 256, 0, stream>>>(W1, W2, W3, w1t, w2t, w3t);

    const int GB = (N_NODES + 127) / 128;  // 391

    // ---- layer 1: A = x fp32 (identity affine), BN=128 (2 heads/block) ----
    gemm_fused_kernel<128, 256, 128, false><<<dim3(GB, 2), 256, 0, stream>>>(
        x, w1t, hbf, nullptr, nullptr, nullptr, a_src1, a_dst1, as_, ad_);
    agg4_kernel<<<(N_NODES + 15) / 16, 256, 0, stream>>>(hbf, as_, ad_, rowptr, srcs, b1, hagg);
    bn_stats_bf16<256><<<128, 256, 0, stream>>>(hagg, statsA);

    // ---- layer 2: A = hagg bf16 + BN(statsA) affine ----
    gemm_fused_kernel<256, 256, 128, true><<<dim3(GB, 2), 256, 0, stream>>>(
        hagg, w2t, hbf, statsA, g1, be1, a_src2, a_dst2, as_, ad_);
    agg4_kernel<<<(N_NODES + 15) / 16, 256, 0, stream>>>(hbf, as_, ad_, rowptr, srcs, b2, hagg);
    bn_stats_bf16<256><<<128, 256, 0, stream>>>(hagg, statsB);

    // ---- layer 3: A = hagg bf16 + BN(statsB) affine, BN=64 ----
    gemm_fused_kernel<256, 64, 64, true><<<dim3(GB, 1), 256, 0, stream>>>(
        hagg, w3t, hbf, statsB, g2, be2, a_src3, a_dst3, as_, ad_);
    agg1_kernel<<<(N_NODES + 31) / 32, 256, 0, stream>>>(hbf, as_, ad_, rowptr, srcs, b3, hagg);
    bn_stats_bf16<64><<<128, 256, 0, stream>>>(hagg, statsC);

    // ---- pool (BN3 affine fused) + FC ----
    pool2_kernel<<<NUM_GRAPHS, 256, 0, stream>>>(hagg, goff, statsC, g3, be3, pooled);
    fc_kernel<<<3, 256, 0, stream>>>(pooled, fcW, fcb, out);
}